// Round 11
// baseline (609.457 us; speedup 1.0000x reference)
//
#include <hip/hip_runtime.h>
#include <hip/hip_bf16.h>

#define N_NODES 50000
#define E_TOTAL 800000
#define IN      128
#define HID     128
#define EPB     64
#define XOFF    ((size_t)N_NODES * HID)
#define FP      296     // old-path fbuf pitch
#define H1OFF   160
#define HP      136
#define CP      264

typedef __attribute__((ext_vector_type(8))) short short8v;
typedef __attribute__((ext_vector_type(4))) float f32x4;

__device__ __forceinline__ float silu_f(float x) { return x / (1.0f + __expf(-x)); }

__device__ __forceinline__ uint pkbf(float lo, float hi) {
    float2 f; f.x = lo; f.y = hi;
    __hip_bfloat162 h = __float22bfloat162_rn(f);
    union { __hip_bfloat162 h; uint u; } c; c.h = h;
    return c.u;
}

__device__ __forceinline__ ushort f2bf(float x) {
    uint u = __float_as_uint(x);
    u += 0x7fff + ((u >> 16) & 1);
    return (ushort)(u >> 16);
}

__device__ __forceinline__ float bf2f(short s) {
    return __uint_as_float(((uint)(ushort)s) << 16);
}

// ---------------------------------------------------------------------------
// prep: pack weights into MFMA fragment order; cmb table; optional nfb.
// ---------------------------------------------------------------------------
__global__ __launch_bounds__(256) void prep_kernel(
    const float* __restrict__ eW1, const float* __restrict__ eW2,
    const float* __restrict__ cW1, const float* __restrict__ nW1,
    const float* __restrict__ nW2, const float* __restrict__ eb1,
    const float* __restrict__ node_feat,
    ushort* __restrict__ pk1old, ushort* __restrict__ pka, ushort* __restrict__ pkb,
    ushort* __restrict__ pk2, ushort* __restrict__ pk3,
    ushort* __restrict__ pkn1, ushort* __restrict__ pkn2,
    float* __restrict__ cmb, ushort* __restrict__ nfb, int do_nfb)
{
    int id = blockIdx.x * 256 + threadIdx.x;
    if (id < 18944) {
        const float* W; ushort* dp; int K, idx;
        if (id < 4608)       { idx = id;         W = eW1;            dp = pk1old; K = 259; }
        else if (id < 6656)  { idx = id - 4608;  W = eW1;            dp = pka;    K = 128; }
        else if (id < 8704)  { idx = id - 6656;  W = eW1 + 128*128;  dp = pkb;    K = 128; }
        else if (id < 10752) { idx = id - 8704;  W = eW2;            dp = pk2;    K = 128; }
        else if (id < 12800) { idx = id - 10752; W = cW1;            dp = pk3;    K = 128; }
        else if (id < 16896) { idx = id - 12800; W = nW1;            dp = pkn1;   K = 256; }
        else                 { idx = id - 16896; W = nW2;            dp = pkn2;   K = 128; }
        int kt = idx >> 9, n = (idx >> 6) & 7, ll = idx & 63;
        int col = (n << 4) + (ll & 15);
        short8v o;
#pragma unroll
        for (int j = 0; j < 8; ++j) {
            int k = (kt << 5) + ((ll >> 4) << 3) + j;
            o[j] = (k < K) ? (short)f2bf(W[(size_t)k * 128 + col]) : (short)0;
        }
        *reinterpret_cast<short8v*>(dp + (size_t)idx * 8) = o;
    } else if (id < 19072) {
        int c = id - 18944;
        cmb[c*4+0] = eW1[256*128 + c];
        cmb[c*4+1] = eW1[257*128 + c];
        cmb[c*4+2] = eW1[258*128 + c];
        cmb[c*4+3] = eb1[c];
    } else if (do_nfb) {
        int idx = id - 19072;
        if (idx < N_NODES * 16) {
            const float4* s = reinterpret_cast<const float4*>(node_feat + (size_t)idx * 8);
            float4 a = s[0], b = s[1];
            uint4 u;
            u.x = pkbf(a.x, a.y); u.y = pkbf(a.z, a.w);
            u.z = pkbf(b.x, b.y); u.w = pkbf(b.z, b.w);
            *reinterpret_cast<uint4*>(nfb + (size_t)idx * 8) = u;
        }
    }
}

// ---------------------------------------------------------------------------
// CSR build: histogram -> 3-pass scan -> scatter permutation.
// ---------------------------------------------------------------------------
__global__ __launch_bounds__(256) void hist_kernel(
    const int* __restrict__ dst, int* __restrict__ cnt)
{
    int e = blockIdx.x * 256 + threadIdx.x;
    if (e < E_TOTAL) atomicAdd(&cnt[dst[e]], 1);
}

__global__ __launch_bounds__(1024) void scan_a(
    const int* __restrict__ cnt, int* __restrict__ part)
{
    __shared__ int ws[16];
    int t = threadIdx.x, lane = t & 63, wv = t >> 6;
    int i = blockIdx.x * 1024 + t;
    int v = (i < N_NODES) ? cnt[i] : 0;
#pragma unroll
    for (int off = 32; off >= 1; off >>= 1) v += __shfl_xor(v, off);
    if (lane == 0) ws[wv] = v;
    __syncthreads();
    if (t < 16) {
        int s = ws[t];
#pragma unroll
        for (int off = 8; off >= 1; off >>= 1) s += __shfl_xor(s, off);
        if (t == 0) part[blockIdx.x] = s;
    }
}

__global__ __launch_bounds__(64) void scan_b(int* __restrict__ part, int n)
{
    int t = threadIdx.x;
    int v = (t < n) ? part[t] : 0;
    int x = v;
#pragma unroll
    for (int off = 1; off < 64; off <<= 1) {
        int y = __shfl_up(x, off);
        if (t >= off) x += y;
    }
    if (t < n) part[t] = x - v;   // exclusive
}

__global__ __launch_bounds__(1024) void scan_c(
    int* __restrict__ cnt, const int* __restrict__ part, int* __restrict__ ptr2)
{
    __shared__ int ws[16];
    int t = threadIdx.x, lane = t & 63, wv = t >> 6;
    int i = blockIdx.x * 1024 + t;
    int v = (i < N_NODES) ? cnt[i] : 0;
    int x = v;
#pragma unroll
    for (int off = 1; off < 64; off <<= 1) {
        int y = __shfl_up(x, off);
        if (lane >= off) x += y;
    }
    if (lane == 63) ws[wv] = x;
    __syncthreads();
    if (t < 16) {
        int s = ws[t], xx = s;
#pragma unroll
        for (int off = 1; off < 16; off <<= 1) {
            int y = __shfl_up(xx, off);
            if (t >= off) xx += y;
        }
        ws[t] = xx - s;
    }
    __syncthreads();
    int excl = part[blockIdx.x] + ws[wv] + x - v;
    if (i < N_NODES) { cnt[i] = excl; ptr2[i] = excl; }
    if (i == N_NODES - 1) { cnt[N_NODES] = E_TOTAL; ptr2[N_NODES] = E_TOTAL; }
}

__global__ __launch_bounds__(256) void scatter_kernel(
    const int* __restrict__ dst, int* __restrict__ ptr2, int* __restrict__ perm)
{
    int e = blockIdx.x * 256 + threadIdx.x;
    if (e < E_TOTAL) {
        int p = atomicAdd(&ptr2[dst[e]], 1);
        perm[p] = e;
    }
}

// ---------------------------------------------------------------------------
// ygemm: ya = h@eW1[0:128] + eb1 (bias folded);  yb = h@eW1[128:256].
// ---------------------------------------------------------------------------
__global__ __launch_bounds__(256) void ygemm_kernel(
    const float* __restrict__ node_feat,
    const ushort* __restrict__ pka, const ushort* __restrict__ pkb,
    const float* __restrict__ eb1,
    ushort* __restrict__ y)
{
    __shared__ __attribute__((aligned(16))) ushort catb[32][HP];
    __shared__ __attribute__((aligned(16))) ushort ybuf[32][CP];

    const int t   = threadIdx.x;
    const int l   = t & 63;
    const int ch  = t >> 6;
    const int r16 = l & 15;
    const int g   = l >> 4;
    const int nb  = blockIdx.x * 32;

    {
        int nd = t >> 3;
        int c  = (t & 7) << 4;
        int gn = nb + nd; if (gn >= N_NODES) gn = N_NODES - 1;
        const float4* sp = reinterpret_cast<const float4*>(node_feat + (size_t)gn * 128 + c);
        float4 a = sp[0], b = sp[1], cc = sp[2], dd = sp[3];
        uint4 u0, u1;
        u0.x = pkbf(a.x, a.y);  u0.y = pkbf(a.z, a.w);
        u0.z = pkbf(b.x, b.y);  u0.w = pkbf(b.z, b.w);
        u1.x = pkbf(cc.x, cc.y); u1.y = pkbf(cc.z, cc.w);
        u1.z = pkbf(dd.x, dd.y); u1.w = pkbf(dd.z, dd.w);
        *reinterpret_cast<uint4*>(&catb[nd][c])     = u0;
        *reinterpret_cast<uint4*>(&catb[nd][c + 8]) = u1;
    }
    __syncthreads();

    const f32x4 zero = {0.f, 0.f, 0.f, 0.f};
    const short8v* pa = reinterpret_cast<const short8v*>((ch < 2) ? pka : pkb);
    const int nbase = (ch & 1) << 2;

    f32x4 acc[2][4];
#pragma unroll
    for (int et = 0; et < 2; ++et)
#pragma unroll
        for (int nt = 0; nt < 4; ++nt) acc[et][nt] = zero;

    for (int kt = 0; kt < 4; ++kt) {
        short8v b0 = *reinterpret_cast<const short8v*>(&catb[r16][(kt << 5) + (g << 3)]);
        short8v b1 = *reinterpret_cast<const short8v*>(&catb[16 + r16][(kt << 5) + (g << 3)]);
#pragma unroll
        for (int nt = 0; nt < 4; ++nt) {
            short8v a = pa[(((kt << 3) + nbase + nt) << 6) + l];
            acc[0][nt] = __builtin_amdgcn_mfma_f32_16x16x32_bf16(a, b0, acc[0][nt], 0, 0, 0);
            acc[1][nt] = __builtin_amdgcn_mfma_f32_16x16x32_bf16(a, b1, acc[1][nt], 0, 0, 0);
        }
    }
#pragma unroll
    for (int nt = 0; nt < 4; ++nt) {
        int cb = (ch << 6) + (nt << 4) + (g << 2);
        float4 bias = {0.f, 0.f, 0.f, 0.f};
        if (ch < 2) bias = *reinterpret_cast<const float4*>(&eb1[cb]);
#pragma unroll
        for (int et = 0; et < 2; ++et) {
            f32x4 v = acc[et][nt];
            uint2 p;
            p.x = pkbf(v[0] + bias.x, v[1] + bias.y);
            p.y = pkbf(v[2] + bias.z, v[3] + bias.w);
            *reinterpret_cast<uint2*>(&ybuf[(et << 4) + r16][cb]) = p;
        }
    }
    __syncthreads();

#pragma unroll
    for (int i = 0; i < 4; ++i) {
        int idx = t + (i << 8);
        int nd  = idx >> 5;
        int c16 = (idx & 31) << 3;
        int gn  = nb + nd;
        if (gn < N_NODES)
            *reinterpret_cast<short8v*>(y + (size_t)gn * 256 + c16) =
                *reinterpret_cast<const short8v*>(&ybuf[nd][c16]);
    }
}

// ---------------------------------------------------------------------------
// NEW edge kernel: no GEMM1. h1 = silu(ya[src]+yb[dst]+r*wr+ef·We+b).
// 512 thr = 8 waves, EPB=64 dst-sorted edges.
// ---------------------------------------------------------------------------
__global__ __launch_bounds__(512, 4) void edge2_kernel(
    const ushort* __restrict__ y, const float* __restrict__ coord,
    const float* __restrict__ edge_feat,
    const int* __restrict__ src, const int* __restrict__ dst,
    const int* __restrict__ perm,
    const float* __restrict__ cmb,
    const ushort* __restrict__ pk2, const ushort* __restrict__ pk3,
    const float* __restrict__ eb2,
    const float* __restrict__ cb1, const float* __restrict__ cW2,
    float* __restrict__ hacc, float* __restrict__ xacc)
{
    __shared__ __attribute__((aligned(16))) ushort h1buf[EPB][HP];
    __shared__ __attribute__((aligned(16))) ushort msgbuf[EPB][HP];
    __shared__ int   sbuf[EPB], dbuf[EPB];
    __shared__ float xdbuf[EPB][4];
    __shared__ float rbuf[EPB][4];
    __shared__ float pbuf[4][EPB];

    const int t   = threadIdx.x;
    const int l   = t & 63;
    const int w   = t >> 6;
    const int ch  = w & 3;
    const int eh  = w >> 2;
    const int r16 = l & 15;
    const int g   = l >> 4;
    const int e_base = blockIdx.x * EPB;

    if (t < EPB) {
        int ee = perm[e_base + t];
        int s = src[ee], d = dst[ee];
        sbuf[t] = s; dbuf[t] = d;
        float dx = coord[(size_t)s*3+0] - coord[(size_t)d*3+0];
        float dy = coord[(size_t)s*3+1] - coord[(size_t)d*3+1];
        float dz = coord[(size_t)s*3+2] - coord[(size_t)d*3+2];
        float radial = dx*dx + dy*dy + dz*dz;
        float inv = 1.0f / (sqrtf(radial) + 1e-30f);
        xdbuf[t][0] = dx * inv; xdbuf[t][1] = dy * inv; xdbuf[t][2] = dz * inv;
        rbuf[t][0] = radial;
        rbuf[t][1] = edge_feat[(size_t)ee*2 + 0];
        rbuf[t][2] = edge_feat[(size_t)ee*2 + 1];
    }
    __syncthreads();

    // ---- gather-combine -> h1 ----
    {
        const int c = (t & 15) << 3;
        const float4* cmb4 = reinterpret_cast<const float4*>(cmb);
#pragma unroll
        for (int p = 0; p < 2; ++p) {
            int e = (t >> 4) + (p << 5);
            short8v a8 = *reinterpret_cast<const short8v*>(y + (size_t)sbuf[e] * 256 + c);
            short8v b8 = *reinterpret_cast<const short8v*>(y + (size_t)dbuf[e] * 256 + 128 + c);
            float r = rbuf[e][0], f0 = rbuf[e][1], f1 = rbuf[e][2];
            float vv[8];
#pragma unroll
            for (int j = 0; j < 8; ++j) {
                float4 q = cmb4[c + j];
                float sv = bf2f(a8[j]) + bf2f(b8[j]);
                sv = fmaf(r, q.x, sv);
                sv = fmaf(f0, q.y, sv);
                sv = fmaf(f1, q.z, sv);
                vv[j] = silu_f(sv);
            }
            uint4 u;
            u.x = pkbf(vv[0], vv[1]); u.y = pkbf(vv[2], vv[3]);
            u.z = pkbf(vv[4], vv[5]); u.w = pkbf(vv[6], vv[7]);
            *reinterpret_cast<uint4*>(&h1buf[e][c]) = u;
        }
    }
    __syncthreads();

    const f32x4 zero = {0.f, 0.f, 0.f, 0.f};
    const short8v* pkv2 = reinterpret_cast<const short8v*>(pk2);
    const short8v* pkv3 = reinterpret_cast<const short8v*>(pk3);

    // ---- GEMM2: K=128 -> silu -> msg ----
    f32x4 acc[2][2];
    acc[0][0] = zero; acc[0][1] = zero; acc[1][0] = zero; acc[1][1] = zero;
    for (int kt = 0; kt < 4; ++kt) {
        short8v b0 = *reinterpret_cast<const short8v*>(&h1buf[(eh << 5) + r16][(kt << 5) + (g << 3)]);
        short8v b1 = *reinterpret_cast<const short8v*>(&h1buf[(eh << 5) + 16 + r16][(kt << 5) + (g << 3)]);
#pragma unroll
        for (int nt = 0; nt < 2; ++nt) {
            short8v a = pkv2[(((kt << 3) + (ch << 1) + nt) << 6) + l];
            acc[0][nt] = __builtin_amdgcn_mfma_f32_16x16x32_bf16(a, b0, acc[0][nt], 0, 0, 0);
            acc[1][nt] = __builtin_amdgcn_mfma_f32_16x16x32_bf16(a, b1, acc[1][nt], 0, 0, 0);
        }
    }
#pragma unroll
    for (int nt = 0; nt < 2; ++nt) {
        int cb = (ch << 5) + (nt << 4) + (g << 2);
        float4 bias = *reinterpret_cast<const float4*>(&eb2[cb]);
#pragma unroll
        for (int et = 0; et < 2; ++et) {
            int e = (eh << 5) + (et << 4) + r16;
            f32x4 v = acc[et][nt];
            uint2 p;
            p.x = pkbf(silu_f(v[0] + bias.x), silu_f(v[1] + bias.y));
            p.y = pkbf(silu_f(v[2] + bias.z), silu_f(v[3] + bias.w));
            *reinterpret_cast<uint2*>(&msgbuf[e][cb]) = p;
        }
    }
    __syncthreads();

    // ---- segmented reduce + flush (dst-sorted runs) ----
    {
        const int c = t & 127;
        const int q = t >> 7;
        float sum = 0.f;
        int cur = dbuf[q << 4];
#pragma unroll
        for (int i = 0; i < 16; ++i) {
            int e = (q << 4) + i;
            sum += __uint_as_float((uint)msgbuf[e][c] << 16);
            int nxt = (i < 15) ? dbuf[e + 1] : -1;
            if (nxt != cur) {
                atomicAdd(&hacc[(size_t)cur * HID + c], sum);
                sum = 0.f; cur = nxt;
            }
        }
    }

    // ---- GEMM3: K=128 -> silu -> dot cW2 ----
    acc[0][0] = zero; acc[0][1] = zero; acc[1][0] = zero; acc[1][1] = zero;
    for (int kt = 0; kt < 4; ++kt) {
        short8v b0 = *reinterpret_cast<const short8v*>(&msgbuf[(eh << 5) + r16][(kt << 5) + (g << 3)]);
        short8v b1 = *reinterpret_cast<const short8v*>(&msgbuf[(eh << 5) + 16 + r16][(kt << 5) + (g << 3)]);
#pragma unroll
        for (int nt = 0; nt < 2; ++nt) {
            short8v a = pkv3[(((kt << 3) + (ch << 1) + nt) << 6) + l];
            acc[0][nt] = __builtin_amdgcn_mfma_f32_16x16x32_bf16(a, b0, acc[0][nt], 0, 0, 0);
            acc[1][nt] = __builtin_amdgcn_mfma_f32_16x16x32_bf16(a, b1, acc[1][nt], 0, 0, 0);
        }
    }
    float part[2] = {0.f, 0.f};
#pragma unroll
    for (int nt = 0; nt < 2; ++nt) {
        int cb = (ch << 5) + (nt << 4) + (g << 2);
        float4 bias = *reinterpret_cast<const float4*>(&cb1[cb]);
        float4 cw   = *reinterpret_cast<const float4*>(&cW2[cb]);
#pragma unroll
        for (int et = 0; et < 2; ++et) {
            f32x4 v = acc[et][nt];
            part[et] += silu_f(v[0] + bias.x) * cw.x + silu_f(v[1] + bias.y) * cw.y
                      + silu_f(v[2] + bias.z) * cw.z + silu_f(v[3] + bias.w) * cw.w;
        }
    }
#pragma unroll
    for (int et = 0; et < 2; ++et) {
        part[et] += __shfl_xor(part[et], 16);
        part[et] += __shfl_xor(part[et], 32);
    }
    if (l < 16) {
        pbuf[ch][(eh << 5) + r16]      = part[0];
        pbuf[ch][(eh << 5) + 16 + r16] = part[1];
    }
    __syncthreads();

    if (t < EPB) {
        float s = pbuf[0][t] + pbuf[1][t] + pbuf[2][t] + pbuf[3][t];
        int gd = dbuf[t];
        atomicAdd(&xacc[(size_t)gd*3 + 0], s * xdbuf[t][0]);
        atomicAdd(&xacc[(size_t)gd*3 + 1], s * xdbuf[t][1]);
        atomicAdd(&xacc[(size_t)gd*3 + 2], s * xdbuf[t][2]);
    }
}

// ---------------------------------------------------------------------------
// OLD edge kernel (r6) — fallback when ws can't hold y.
// ---------------------------------------------------------------------------
template<bool NFB>
__global__ __launch_bounds__(512, 8) void edge_kernel(
    const float* __restrict__ node_feat, const ushort* __restrict__ nfb,
    const float* __restrict__ coord, const float* __restrict__ edge_feat,
    const int* __restrict__ src, const int* __restrict__ dst,
    const int* __restrict__ perm, int use_perm,
    const ushort* __restrict__ pk1, const ushort* __restrict__ pk2,
    const ushort* __restrict__ pk3,
    const float* __restrict__ eb1, const float* __restrict__ eb2,
    const float* __restrict__ cb1, const float* __restrict__ cW2,
    float* __restrict__ hacc, float* __restrict__ xacc)
{
    __shared__ __attribute__((aligned(16))) ushort fbuf[EPB][FP];
    __shared__ int   sbuf[EPB], dbuf[EPB];
    __shared__ float xdbuf[EPB][4];
    __shared__ float pbuf[4][EPB];

    const int t   = threadIdx.x;
    const int l   = t & 63;
    const int w   = t >> 6;
    const int ch  = w & 3;
    const int eh  = w >> 2;
    const int r16 = l & 15;
    const int g   = l >> 4;
    const int e_base = blockIdx.x * EPB;

    int ee = 0;
    if (t < EPB) {
        ee = use_perm ? perm[e_base + t] : (e_base + t);
        sbuf[t] = src[ee];
        dbuf[t] = dst[ee];
    }
    __syncthreads();

    {
        const int e = t >> 3;
        const int c = (t & 7) << 5;
        if (NFB) {
            const ushort* sp = (c < 128) ? nfb + (size_t)sbuf[e] * 128 + c
                                         : nfb + (size_t)dbuf[e] * 128 + (c - 128);
            const short8v* spv = reinterpret_cast<const short8v*>(sp);
#pragma unroll
            for (int i = 0; i < 4; ++i)
                *reinterpret_cast<short8v*>(&fbuf[e][c + (i << 3)]) = spv[i];
        } else {
            const float* sp = (c < 128) ? node_feat + (size_t)sbuf[e] * 128 + c
                                        : node_feat + (size_t)dbuf[e] * 128 + (c - 128);
            const float4* spv = reinterpret_cast<const float4*>(sp);
#pragma unroll
            for (int i = 0; i < 4; ++i) {
                float4 a = spv[2 * i], b = spv[2 * i + 1];
                uint4 u;
                u.x = pkbf(a.x, a.y); u.y = pkbf(a.z, a.w);
                u.z = pkbf(b.x, b.y); u.w = pkbf(b.z, b.w);
                *reinterpret_cast<uint4*>(&fbuf[e][c + (i << 3)]) = u;
            }
        }
    }
    if (t < EPB) {
        const int e = t, s = sbuf[e], d = dbuf[e];
        float dx = coord[(size_t)s*3+0] - coord[(size_t)d*3+0];
        float dy = coord[(size_t)s*3+1] - coord[(size_t)d*3+1];
        float dz = coord[(size_t)s*3+2] - coord[(size_t)d*3+2];
        float radial = dx*dx + dy*dy + dz*dz;
        float inv = 1.0f / (sqrtf(radial) + 1e-30f);
        fbuf[e][256] = f2bf(radial);
        fbuf[e][257] = f2bf(edge_feat[(size_t)ee*2 + 0]);
        fbuf[e][258] = f2bf(edge_feat[(size_t)ee*2 + 1]);
#pragma unroll
        for (int k = 259; k < 288; ++k) fbuf[e][k] = 0;
        xdbuf[e][0] = dx * inv; xdbuf[e][1] = dy * inv; xdbuf[e][2] = dz * inv;
    }
    __syncthreads();

    const f32x4 zero = {0.f, 0.f, 0.f, 0.f};
    const short8v* pkv1 = reinterpret_cast<const short8v*>(pk1);
    const short8v* pkv2 = reinterpret_cast<const short8v*>(pk2);
    const short8v* pkv3 = reinterpret_cast<const short8v*>(pk3);

    f32x4 acc[2][2];
    acc[0][0] = zero; acc[0][1] = zero; acc[1][0] = zero; acc[1][1] = zero;
    for (int kt = 0; kt < 9; ++kt) {
        short8v b0 = *reinterpret_cast<const short8v*>(&fbuf[(eh << 5) + r16][(kt << 5) + (g << 3)]);
        short8v b1 = *reinterpret_cast<const short8v*>(&fbuf[(eh << 5) + 16 + r16][(kt << 5) + (g << 3)]);
#pragma unroll
        for (int nt = 0; nt < 2; ++nt) {
            short8v a = pkv1[(((kt << 3) + (ch << 1) + nt) << 6) + l];
            acc[0][nt] = __builtin_amdgcn_mfma_f32_16x16x32_bf16(a, b0, acc[0][nt], 0, 0, 0);
            acc[1][nt] = __builtin_amdgcn_mfma_f32_16x16x32_bf16(a, b1, acc[1][nt], 0, 0, 0);
        }
    }
    __syncthreads();
#pragma unroll
    for (int nt = 0; nt < 2; ++nt) {
        int cb = (ch << 5) + (nt << 4) + (g << 2);
        float4 bias = *reinterpret_cast<const float4*>(&eb1[cb]);
#pragma unroll
        for (int et = 0; et < 2; ++et) {
            int e = (eh << 5) + (et << 4) + r16;
            f32x4 v = acc[et][nt];
            uint2 p;
            p.x = pkbf(silu_f(v[0] + bias.x), silu_f(v[1] + bias.y));
            p.y = pkbf(silu_f(v[2] + bias.z), silu_f(v[3] + bias.w));
            *reinterpret_cast<uint2*>(&fbuf[e][H1OFF + cb]) = p;
        }
    }
    __syncthreads();

    acc[0][0] = zero; acc[0][1] = zero; acc[1][0] = zero; acc[1][1] = zero;
    for (int kt = 0; kt < 4; ++kt) {
        short8v b0 = *reinterpret_cast<const short8v*>(&fbuf[(eh << 5) + r16][H1OFF + (kt << 5) + (g << 3)]);
        short8v b1 = *reinterpret_cast<const short8v*>(&fbuf[(eh << 5) + 16 + r16][H1OFF + (kt << 5) + (g << 3)]);
#pragma unroll
        for (int nt = 0; nt < 2; ++nt) {
            short8v a = pkv2[(((kt << 3) + (ch << 1) + nt) << 6) + l];
            acc[0][nt] = __builtin_amdgcn_mfma_f32_16x16x32_bf16(a, b0, acc[0][nt], 0, 0, 0);
            acc[1][nt] = __builtin_amdgcn_mfma_f32_16x16x32_bf16(a, b1, acc[1][nt], 0, 0, 0);
        }
    }
#pragma unroll
    for (int nt = 0; nt < 2; ++nt) {
        int cb = (ch << 5) + (nt << 4) + (g << 2);
        float4 bias = *reinterpret_cast<const float4*>(&eb2[cb]);
#pragma unroll
        for (int et = 0; et < 2; ++et) {
            int e = (eh << 5) + (et << 4) + r16;
            f32x4 v = acc[et][nt];
            uint2 p;
            p.x = pkbf(silu_f(v[0] + bias.x), silu_f(v[1] + bias.y));
            p.y = pkbf(silu_f(v[2] + bias.z), silu_f(v[3] + bias.w));
            *reinterpret_cast<uint2*>(&fbuf[e][cb]) = p;
        }
    }
    __syncthreads();

    {
        const int c = t & 127;
        const int q = t >> 7;
        float sum = 0.f;
        int cur = dbuf[q << 4];
#pragma unroll
        for (int i = 0; i < 16; ++i) {
            int e = (q << 4) + i;
            sum += __uint_as_float((uint)fbuf[e][c] << 16);
            int nxt = (i < 15) ? dbuf[e + 1] : -1;
            if (nxt != cur) {
                atomicAdd(&hacc[(size_t)cur * HID + c], sum);
                sum = 0.f; cur = nxt;
            }
        }
    }

    acc[0][0] = zero; acc[0][1] = zero; acc[1][0] = zero; acc[1][1] = zero;
    for (int kt = 0; kt < 4; ++kt) {
        short8v b0 = *reinterpret_cast<const short8v*>(&fbuf[(eh << 5) + r16][(kt << 5) + (g << 3)]);
        short8v b1 = *reinterpret_cast<const short8v*>(&fbuf[(eh << 5) + 16 + r16][(kt << 5) + (g << 3)]);
#pragma unroll
        for (int nt = 0; nt < 2; ++nt) {
            short8v a = pkv3[(((kt << 3) + (ch << 1) + nt) << 6) + l];
            acc[0][nt] = __builtin_amdgcn_mfma_f32_16x16x32_bf16(a, b0, acc[0][nt], 0, 0, 0);
            acc[1][nt] = __builtin_amdgcn_mfma_f32_16x16x32_bf16(a, b1, acc[1][nt], 0, 0, 0);
        }
    }
    float part[2] = {0.f, 0.f};
#pragma unroll
    for (int nt = 0; nt < 2; ++nt) {
        int cb = (ch << 5) + (nt << 4) + (g << 2);
        float4 bias = *reinterpret_cast<const float4*>(&cb1[cb]);
        float4 cw   = *reinterpret_cast<const float4*>(&cW2[cb]);
#pragma unroll
        for (int et = 0; et < 2; ++et) {
            f32x4 v = acc[et][nt];
            part[et] += silu_f(v[0] + bias.x) * cw.x + silu_f(v[1] + bias.y) * cw.y
                      + silu_f(v[2] + bias.z) * cw.z + silu_f(v[3] + bias.w) * cw.w;
        }
    }
#pragma unroll
    for (int et = 0; et < 2; ++et) {
        part[et] += __shfl_xor(part[et], 16);
        part[et] += __shfl_xor(part[et], 32);
    }
    if (l < 16) {
        pbuf[ch][(eh << 5) + r16]      = part[0];
        pbuf[ch][(eh << 5) + 16 + r16] = part[1];
    }
    __syncthreads();

    if (t < EPB) {
        float s = pbuf[0][t] + pbuf[1][t] + pbuf[2][t] + pbuf[3][t];
        int gd = dbuf[t];
        atomicAdd(&xacc[(size_t)gd*3 + 0], s * xdbuf[t][0]);
        atomicAdd(&xacc[(size_t)gd*3 + 1], s * xdbuf[t][1]);
        atomicAdd(&xacc[(size_t)gd*3 + 2], s * xdbuf[t][2]);
    }
}

// ---------------------------------------------------------------------------
// Node kernel (MFMA): 256 thr = 4 waves, 32 nodes/block. deg from CSR ptr.
// ---------------------------------------------------------------------------
template<bool NFB>
__global__ __launch_bounds__(256) void node_kernel(
    const float* __restrict__ node_feat, const ushort* __restrict__ nfb,
    const float* __restrict__ coord,
    const ushort* __restrict__ pkn1, const ushort* __restrict__ pkn2,
    const float* __restrict__ nb1, const float* __restrict__ nb2,
    float* __restrict__ dout, const int* __restrict__ ptr)
{
    __shared__ __attribute__((aligned(16))) ushort catb[32][CP];
    __shared__ __attribute__((aligned(16))) ushort h1b[32][HP];

    const int t   = threadIdx.x;
    const int l   = t & 63;
    const int w   = t >> 6;
    const int ch  = w & 1;
    const int eh  = w >> 1;
    const int r16 = l & 15;
    const int g   = l >> 4;
    const int nb  = blockIdx.x * 32;

    {
        int nd = t >> 3;
        int c  = (t & 7) << 5;
        int gn = nb + nd; if (gn >= N_NODES) gn = N_NODES - 1;
        if (c < 128) {
            if (NFB) {
                const short8v* spv = reinterpret_cast<const short8v*>(nfb + (size_t)gn * 128 + c);
#pragma unroll
                for (int i = 0; i < 4; ++i)
                    *reinterpret_cast<short8v*>(&catb[nd][c + (i << 3)]) = spv[i];
            } else {
                const float4* spv = reinterpret_cast<const float4*>(node_feat + (size_t)gn * 128 + c);
#pragma unroll
                for (int i = 0; i < 4; ++i) {
                    float4 a = spv[2 * i], b = spv[2 * i + 1];
                    uint4 u;
                    u.x = pkbf(a.x, a.y); u.y = pkbf(a.z, a.w);
                    u.z = pkbf(b.x, b.y); u.w = pkbf(b.z, b.w);
                    *reinterpret_cast<uint4*>(&catb[nd][c + (i << 3)]) = u;
                }
            }
        } else {
            const float4* spv = reinterpret_cast<const float4*>(dout + (size_t)gn * HID + (c - 128));
#pragma unroll
            for (int i = 0; i < 4; ++i) {
                float4 a = spv[2 * i], b = spv[2 * i + 1];
                uint4 u;
                u.x = pkbf(a.x, a.y); u.y = pkbf(a.z, a.w);
                u.z = pkbf(b.x, b.y); u.w = pkbf(b.z, b.w);
                *reinterpret_cast<uint4*>(&catb[nd][c + (i << 3)]) = u;
            }
        }
    }
    __syncthreads();

    const f32x4 zero = {0.f, 0.f, 0.f, 0.f};
    const short8v* pv1 = reinterpret_cast<const short8v*>(pkn1);
    const short8v* pv2 = reinterpret_cast<const short8v*>(pkn2);

    f32x4 acc[4];
#pragma unroll
    for (int nt = 0; nt < 4; ++nt) acc[nt] = zero;
    for (int kt = 0; kt < 8; ++kt) {
        short8v b = *reinterpret_cast<const short8v*>(&catb[(eh << 4) + r16][(kt << 5) + (g << 3)]);
#pragma unroll
        for (int nt = 0; nt < 4; ++nt) {
            short8v a = pv1[(((kt << 3) + (ch << 2) + nt) << 6) + l];
            acc[nt] = __builtin_amdgcn_mfma_f32_16x16x32_bf16(a, b, acc[nt], 0, 0, 0);
        }
    }
#pragma unroll
    for (int nt = 0; nt < 4; ++nt) {
        int cb = (ch << 6) + (nt << 4) + (g << 2);
        float4 bias = *reinterpret_cast<const float4*>(&nb1[cb]);
        int nd = (eh << 4) + r16;
        f32x4 v = acc[nt];
        uint2 p;
        p.x = pkbf(silu_f(v[0] + bias.x), silu_f(v[1] + bias.y));
        p.y = pkbf(silu_f(v[2] + bias.z), silu_f(v[3] + bias.w));
        *reinterpret_cast<uint2*>(&h1b[nd][cb]) = p;
    }
    __syncthreads();

#pragma unroll
    for (int nt = 0; nt < 4; ++nt) acc[nt] = zero;
    for (int kt = 0; kt < 4; ++kt) {
        short8v b = *reinterpret_cast<const short8v*>(&h1b[(eh << 4) + r16][(kt << 5) + (g << 3)]);
#pragma unroll
        for (int nt = 0; nt < 4; ++nt) {
            short8v a = pv2[(((kt << 3) + (ch << 2) + nt) << 6) + l];
            acc[nt] = __builtin_amdgcn_mfma_f32_16x16x32_bf16(a, b, acc[nt], 0, 0, 0);
        }
    }
    {
        int gw = nb + (eh << 4) + r16;
        if (gw < N_NODES) {
#pragma unroll
            for (int nt = 0; nt < 4; ++nt) {
                int cb = (ch << 6) + (nt << 4) + (g << 2);
                float4 bias = *reinterpret_cast<const float4*>(&nb2[cb]);
                f32x4 v = acc[nt];
                float4 o;
                o.x = v[0] + bias.x; o.y = v[1] + bias.y;
                o.z = v[2] + bias.z; o.w = v[3] + bias.w;
                *reinterpret_cast<float4*>(&dout[(size_t)gw * HID + cb]) = o;
            }
        }
    }

    if (t < 96) {
        int nd = t / 3, d = t - 3 * nd;
        int gn = nb + nd;
        if (gn < N_NODES) {
            size_t xi = XOFF + (size_t)gn * 3 + d;
            float dg = (float)(ptr[gn + 1] - ptr[gn]);
            dg = dg > 1.0f ? dg : 1.0f;
            dout[xi] = coord[(size_t)gn * 3 + d] + dout[xi] / dg;
        }
    }
}

extern "C" void kernel_launch(void* const* d_in, const int* in_sizes, int n_in,
                              void* d_out, int out_size, void* d_ws, size_t ws_size,
                              hipStream_t stream) {
    const float* node_feat = (const float*)d_in[0];
    const float* coord     = (const float*)d_in[1];
    const float* edge_feat = (const float*)d_in[2];
    const int*   src       = (const int*)d_in[3];
    const int*   dst       = (const int*)d_in[4];
    const float* eW1 = (const float*)d_in[5];
    const float* eb1 = (const float*)d_in[6];
    const float* eW2 = (const float*)d_in[7];
    const float* eb2 = (const float*)d_in[8];
    const float* nW1 = (const float*)d_in[9];
    const float* nb1 = (const float*)d_in[10];
    const float* nW2 = (const float*)d_in[11];
    const float* nb2 = (const float*)d_in[12];
    const float* cW1 = (const float*)d_in[13];
    const float* cb1 = (const float*)d_in[14];
    const float* cW2 = (const float*)d_in[15];

    float* out = (float*)d_out;
    char* base = (char*)d_ws;
    // ws layout (bytes):
    int*    ptrb   = (int*)base;                      // 0       .. 200064
    int*    part   = (int*)(base + 200064);           // 200064  .. 200320
    int*    ptr2   = (int*)(base + 200320);           // 200320  .. 400384
    ushort* pk1old = (ushort*)(base + 400384);        // 400384  .. 474112
    ushort* pka    = (ushort*)(base + 474112);        // 474112  .. 506880
    ushort* pkb    = (ushort*)(base + 506880);        // 506880  .. 539648
    ushort* pk2    = (ushort*)(base + 539648);        // 539648  .. 572416
    ushort* pk3    = (ushort*)(base + 572416);        // 572416  .. 605184
    ushort* pkn1   = (ushort*)(base + 605184);        // 605184  .. 670720
    ushort* pkn2   = (ushort*)(base + 670720);        // 670720  .. 703488
    float*  cmb    = (float*)(base + 703488);         // 703488  .. 705536
    int*    perm   = (int*)(base + 705536);           // 705536  .. 3905536
    ushort* ybuf   = (ushort*)(base + 3905536);       // y: +25.6MB | nfb: +12.8MB
    const size_t need_y    = 3905536 + (size_t)N_NODES * 256 * 2;   // 29505536
    const size_t need_nfb  = 3905536 + (size_t)N_NODES * 128 * 2;   // 16705536
    const size_t need_perm = 3905536;
    const bool use_y    = ws_size >= need_y;
    const bool use_nfb  = !use_y && ws_size >= need_nfb;
    const bool use_perm = ws_size >= need_perm;

    hipMemsetAsync(d_out, 0, (size_t)out_size * sizeof(float), stream);
    hipMemsetAsync(d_ws, 0, 200064, stream);

    int prep_grid = (use_nfb ? (19072 + N_NODES * 16) + 255 : 19072 + 255) / 256;
    prep_kernel<<<prep_grid, 256, 0, stream>>>(
        eW1, eW2, cW1, nW1, nW2, eb1, node_feat,
        pk1old, pka, pkb, pk2, pk3, pkn1, pkn2, cmb, ybuf, use_nfb ? 1 : 0);

    hist_kernel<<<(E_TOTAL + 255) / 256, 256, 0, stream>>>(dst, ptrb);
    scan_a<<<49, 1024, 0, stream>>>(ptrb, part);
    scan_b<<<1, 64, 0, stream>>>(part, 49);
    scan_c<<<49, 1024, 0, stream>>>(ptrb, part, ptr2);
    if (use_perm)
        scatter_kernel<<<(E_TOTAL + 255) / 256, 256, 0, stream>>>(dst, ptr2, perm);

    if (use_y) {
        ygemm_kernel<<<(N_NODES + 31) / 32, 256, 0, stream>>>(node_feat, pka, pkb, eb1, ybuf);
        edge2_kernel<<<E_TOTAL / EPB, 512, 0, stream>>>(
            ybuf, coord, edge_feat, src, dst, perm, cmb,
            pk2, pk3, eb2, cb1, cW2, out, out + XOFF);
        node_kernel<false><<<(N_NODES + 31) / 32, 256, 0, stream>>>(
            node_feat, ybuf, coord, pkn1, pkn2, nb1, nb2, out, ptrb);
    } else if (use_nfb) {
        edge_kernel<true><<<E_TOTAL / EPB, 512, 0, stream>>>(
            node_feat, ybuf, coord, edge_feat, src, dst, perm, use_perm ? 1 : 0,
            pk1old, pk2, pk3, eb1, eb2, cb1, cW2, out, out + XOFF);
        node_kernel<true><<<(N_NODES + 31) / 32, 256, 0, stream>>>(
            node_feat, ybuf, coord, pkn1, pkn2, nb1, nb2, out, ptrb);
    } else {
        edge_kernel<false><<<E_TOTAL / EPB, 512, 0, stream>>>(
            node_feat, ybuf, coord, edge_feat, src, dst, perm, use_perm ? 1 : 0,
            pk1old, pk2, pk3, eb1, eb2, cb1, cW2, out, out + XOFF);
        node_kernel<false><<<(N_NODES + 31) / 32, 256, 0, stream>>>(
            node_feat, ybuf, coord, pkn1, pkn2, nb1, nb2, out, ptrb);
    }
}

// Round 12
// 523.048 us; speedup vs baseline: 1.1652x; 1.1652x over previous
//
#include <hip/hip_runtime.h>
#include <hip/hip_bf16.h>

#define N_NODES 50000
#define E_TOTAL 800000
#define IN      128
#define HID     128
#define EPB     64
#define XOFF    ((size_t)N_NODES * HID)
#define FP      296     // old-path fbuf pitch
#define H1OFF   160
#define HP      136
#define CP      264

typedef __attribute__((ext_vector_type(8))) short short8v;
typedef __attribute__((ext_vector_type(4))) float f32x4;

__device__ __forceinline__ float silu_f(float x) { return x / (1.0f + __expf(-x)); }

__device__ __forceinline__ uint pkbf(float lo, float hi) {
    float2 f; f.x = lo; f.y = hi;
    __hip_bfloat162 h = __float22bfloat162_rn(f);
    union { __hip_bfloat162 h; uint u; } c; c.h = h;
    return c.u;
}

__device__ __forceinline__ ushort f2bf(float x) {
    uint u = __float_as_uint(x);
    u += 0x7fff + ((u >> 16) & 1);
    return (ushort)(u >> 16);
}

__device__ __forceinline__ float bf2f(short s) {
    return __uint_as_float(((uint)(ushort)s) << 16);
}

// ---------------------------------------------------------------------------
// prep: pack weights into MFMA fragment order (entry (kt,n,l)[j] =
// W[kt*32+8*(l>>4)+j][n*16+(l&15)]); cmb table; optional nfb (fallback).
// ids: 0..4607 pk1old | 4608..6655 pka | 6656..8703 pkb | 8704..10751 pk2 |
//      10752..12799 pk3 | 12800..16895 pkn1 | 16896..18943 pkn2 |
//      18944..19071 cmb | 19072.. nfb
// ---------------------------------------------------------------------------
__global__ __launch_bounds__(256) void prep_kernel(
    const float* __restrict__ eW1, const float* __restrict__ eW2,
    const float* __restrict__ cW1, const float* __restrict__ nW1,
    const float* __restrict__ nW2, const float* __restrict__ eb1,
    const float* __restrict__ node_feat,
    ushort* __restrict__ pk1old, ushort* __restrict__ pka, ushort* __restrict__ pkb,
    ushort* __restrict__ pk2, ushort* __restrict__ pk3,
    ushort* __restrict__ pkn1, ushort* __restrict__ pkn2,
    float* __restrict__ cmb, ushort* __restrict__ nfb, int do_nfb)
{
    int id = blockIdx.x * 256 + threadIdx.x;
    if (id < 18944) {
        const float* W; ushort* dp; int K, idx;
        if (id < 4608)       { idx = id;         W = eW1;            dp = pk1old; K = 259; }
        else if (id < 6656)  { idx = id - 4608;  W = eW1;            dp = pka;    K = 128; }
        else if (id < 8704)  { idx = id - 6656;  W = eW1 + 128*128;  dp = pkb;    K = 128; }
        else if (id < 10752) { idx = id - 8704;  W = eW2;            dp = pk2;    K = 128; }
        else if (id < 12800) { idx = id - 10752; W = cW1;            dp = pk3;    K = 128; }
        else if (id < 16896) { idx = id - 12800; W = nW1;            dp = pkn1;   K = 256; }
        else                 { idx = id - 16896; W = nW2;            dp = pkn2;   K = 128; }
        int kt = idx >> 9, n = (idx >> 6) & 7, ll = idx & 63;
        int col = (n << 4) + (ll & 15);
        short8v o;
#pragma unroll
        for (int j = 0; j < 8; ++j) {
            int k = (kt << 5) + ((ll >> 4) << 3) + j;
            o[j] = (k < K) ? (short)f2bf(W[(size_t)k * 128 + col]) : (short)0;
        }
        *reinterpret_cast<short8v*>(dp + (size_t)idx * 8) = o;
    } else if (id < 19072) {
        int c = id - 18944;
        cmb[c*4+0] = eW1[256*128 + c];
        cmb[c*4+1] = eW1[257*128 + c];
        cmb[c*4+2] = eW1[258*128 + c];
        cmb[c*4+3] = eb1[c];
    } else if (do_nfb) {
        int idx = id - 19072;
        if (idx < N_NODES * 16) {
            const float4* s = reinterpret_cast<const float4*>(node_feat + (size_t)idx * 8);
            float4 a = s[0], b = s[1];
            uint4 u;
            u.x = pkbf(a.x, a.y); u.y = pkbf(a.z, a.w);
            u.z = pkbf(b.x, b.y); u.w = pkbf(b.z, b.w);
            *reinterpret_cast<uint4*>(nfb + (size_t)idx * 8) = u;
        }
    }
}

// ---------------------------------------------------------------------------
// CSR build: histogram -> 3-pass scan -> scatter permutation.
// ---------------------------------------------------------------------------
__global__ __launch_bounds__(256) void hist_kernel(
    const int* __restrict__ dst, int* __restrict__ cnt)
{
    int e = blockIdx.x * 256 + threadIdx.x;
    if (e < E_TOTAL) atomicAdd(&cnt[dst[e]], 1);
}

__global__ __launch_bounds__(1024) void scan_a(
    const int* __restrict__ cnt, int* __restrict__ part)
{
    __shared__ int ws[16];
    int t = threadIdx.x, lane = t & 63, wv = t >> 6;
    int i = blockIdx.x * 1024 + t;
    int v = (i < N_NODES) ? cnt[i] : 0;
#pragma unroll
    for (int off = 32; off >= 1; off >>= 1) v += __shfl_xor(v, off);
    if (lane == 0) ws[wv] = v;
    __syncthreads();
    if (t < 16) {
        int s = ws[t];
#pragma unroll
        for (int off = 8; off >= 1; off >>= 1) s += __shfl_xor(s, off);
        if (t == 0) part[blockIdx.x] = s;
    }
}

__global__ __launch_bounds__(64) void scan_b(int* __restrict__ part, int n)
{
    int t = threadIdx.x;
    int v = (t < n) ? part[t] : 0;
    int x = v;
#pragma unroll
    for (int off = 1; off < 64; off <<= 1) {
        int y = __shfl_up(x, off);
        if (t >= off) x += y;
    }
    if (t < n) part[t] = x - v;   // exclusive
}

__global__ __launch_bounds__(1024) void scan_c(
    int* __restrict__ cnt, const int* __restrict__ part, int* __restrict__ ptr2)
{
    __shared__ int ws[16];
    int t = threadIdx.x, lane = t & 63, wv = t >> 6;
    int i = blockIdx.x * 1024 + t;
    int v = (i < N_NODES) ? cnt[i] : 0;
    int x = v;
#pragma unroll
    for (int off = 1; off < 64; off <<= 1) {
        int y = __shfl_up(x, off);
        if (lane >= off) x += y;
    }
    if (lane == 63) ws[wv] = x;
    __syncthreads();
    if (t < 16) {
        int s = ws[t], xx = s;
#pragma unroll
        for (int off = 1; off < 16; off <<= 1) {
            int y = __shfl_up(xx, off);
            if (t >= off) xx += y;
        }
        ws[t] = xx - s;
    }
    __syncthreads();
    int excl = part[blockIdx.x] + ws[wv] + x - v;
    if (i < N_NODES) { cnt[i] = excl; ptr2[i] = excl; }
    if (i == N_NODES - 1) { cnt[N_NODES] = E_TOTAL; ptr2[N_NODES] = E_TOTAL; }
}

__global__ __launch_bounds__(256) void scatter_kernel(
    const int* __restrict__ dst, int* __restrict__ ptr2, int* __restrict__ perm)
{
    int e = blockIdx.x * 256 + threadIdx.x;
    if (e < E_TOTAL) {
        int p = atomicAdd(&ptr2[dst[e]], 1);
        perm[p] = e;
    }
}

// ---------------------------------------------------------------------------
// ygemm: y[n][0:128] = h[n] @ eW1[0:128]; y[n][128:256] = h[n] @ eW1[128:256].
// 256 thr = 4 waves, 32 nodes/block. A=weight frags, B=node frags.
// ---------------------------------------------------------------------------
__global__ __launch_bounds__(256) void ygemm_kernel(
    const float* __restrict__ node_feat,
    const ushort* __restrict__ pka, const ushort* __restrict__ pkb,
    ushort* __restrict__ y)
{
    __shared__ __attribute__((aligned(16))) ushort catb[32][HP];
    __shared__ __attribute__((aligned(16))) ushort ybuf[32][CP];

    const int t   = threadIdx.x;
    const int l   = t & 63;
    const int ch  = t >> 6;        // wave 0..3 -> y cols ch*64..+63
    const int r16 = l & 15;
    const int g   = l >> 4;
    const int nb  = blockIdx.x * 32;

    {   // stage 32 nodes x 128 chans bf16
        int nd = t >> 3;
        int c  = (t & 7) << 4;
        int gn = nb + nd; if (gn >= N_NODES) gn = N_NODES - 1;
        const float4* sp = reinterpret_cast<const float4*>(node_feat + (size_t)gn * 128 + c);
        float4 a = sp[0], b = sp[1], cc = sp[2], dd = sp[3];
        uint4 u0, u1;
        u0.x = pkbf(a.x, a.y);  u0.y = pkbf(a.z, a.w);
        u0.z = pkbf(b.x, b.y);  u0.w = pkbf(b.z, b.w);
        u1.x = pkbf(cc.x, cc.y); u1.y = pkbf(cc.z, cc.w);
        u1.z = pkbf(dd.x, dd.y); u1.w = pkbf(dd.z, dd.w);
        *reinterpret_cast<uint4*>(&catb[nd][c])     = u0;
        *reinterpret_cast<uint4*>(&catb[nd][c + 8]) = u1;
    }
    __syncthreads();

    const f32x4 zero = {0.f, 0.f, 0.f, 0.f};
    const short8v* pa = reinterpret_cast<const short8v*>((ch < 2) ? pka : pkb);
    const int nbase = (ch & 1) << 2;

    f32x4 acc[2][4];
#pragma unroll
    for (int et = 0; et < 2; ++et)
#pragma unroll
        for (int nt = 0; nt < 4; ++nt) acc[et][nt] = zero;

    for (int kt = 0; kt < 4; ++kt) {
        short8v b0 = *reinterpret_cast<const short8v*>(&catb[r16][(kt << 5) + (g << 3)]);
        short8v b1 = *reinterpret_cast<const short8v*>(&catb[16 + r16][(kt << 5) + (g << 3)]);
#pragma unroll
        for (int nt = 0; nt < 4; ++nt) {
            short8v a = pa[(((kt << 3) + nbase + nt) << 6) + l];
            acc[0][nt] = __builtin_amdgcn_mfma_f32_16x16x32_bf16(a, b0, acc[0][nt], 0, 0, 0);
            acc[1][nt] = __builtin_amdgcn_mfma_f32_16x16x32_bf16(a, b1, acc[1][nt], 0, 0, 0);
        }
    }
#pragma unroll
    for (int nt = 0; nt < 4; ++nt) {
        int cb = (ch << 6) + (nt << 4) + (g << 2);
#pragma unroll
        for (int et = 0; et < 2; ++et) {
            f32x4 v = acc[et][nt];
            uint2 p;
            p.x = pkbf(v[0], v[1]); p.y = pkbf(v[2], v[3]);
            *reinterpret_cast<uint2*>(&ybuf[(et << 4) + r16][cb]) = p;
        }
    }
    __syncthreads();

#pragma unroll
    for (int i = 0; i < 4; ++i) {
        int idx = t + (i << 8);
        int nd  = idx >> 5;
        int c16 = (idx & 31) << 3;
        int gn  = nb + nd;
        if (gn < N_NODES)
            *reinterpret_cast<short8v*>(y + (size_t)gn * 256 + c16) =
                *reinterpret_cast<const short8v*>(&ybuf[nd][c16]);
    }
}

// ---------------------------------------------------------------------------
// NEW edge kernel: no GEMM1. h1 = silu(ya[src]+yb[dst]+r*wr+ef·We+b).
// 512 thr = 8 waves, EPB=64 dst-sorted edges.
// ---------------------------------------------------------------------------
__global__ __launch_bounds__(512, 4) void edge2_kernel(
    const ushort* __restrict__ y, const float* __restrict__ coord,
    const float* __restrict__ edge_feat,
    const int* __restrict__ src, const int* __restrict__ dst,
    const int* __restrict__ perm,
    const float* __restrict__ cmb,
    const ushort* __restrict__ pk2, const ushort* __restrict__ pk3,
    const float* __restrict__ eb2,
    const float* __restrict__ cb1, const float* __restrict__ cW2,
    float* __restrict__ hacc, float* __restrict__ xacc)
{
    __shared__ __attribute__((aligned(16))) ushort h1buf[EPB][HP];
    __shared__ __attribute__((aligned(16))) ushort msgbuf[EPB][HP];
    __shared__ int   sbuf[EPB], dbuf[EPB];
    __shared__ float xdbuf[EPB][4];
    __shared__ float rbuf[EPB][4];
    __shared__ float pbuf[4][EPB];

    const int t   = threadIdx.x;
    const int l   = t & 63;
    const int w   = t >> 6;
    const int ch  = w & 3;
    const int eh  = w >> 2;
    const int r16 = l & 15;
    const int g   = l >> 4;
    const int e_base = blockIdx.x * EPB;

    if (t < EPB) {
        int ee = perm[e_base + t];
        int s = src[ee], d = dst[ee];
        sbuf[t] = s; dbuf[t] = d;
        float dx = coord[(size_t)s*3+0] - coord[(size_t)d*3+0];
        float dy = coord[(size_t)s*3+1] - coord[(size_t)d*3+1];
        float dz = coord[(size_t)s*3+2] - coord[(size_t)d*3+2];
        float radial = dx*dx + dy*dy + dz*dz;
        float inv = 1.0f / (sqrtf(radial) + 1e-30f);
        xdbuf[t][0] = dx * inv; xdbuf[t][1] = dy * inv; xdbuf[t][2] = dz * inv;
        rbuf[t][0] = radial;
        rbuf[t][1] = edge_feat[(size_t)ee*2 + 0];
        rbuf[t][2] = edge_feat[(size_t)ee*2 + 1];
    }
    __syncthreads();

    // ---- gather-combine -> h1 ----
    {
        const int c = (t & 15) << 3;
        const float4* cmb4 = reinterpret_cast<const float4*>(cmb);
#pragma unroll
        for (int p = 0; p < 2; ++p) {
            int e = (t >> 4) + (p << 5);
            short8v a8 = *reinterpret_cast<const short8v*>(y + (size_t)sbuf[e] * 256 + c);
            short8v b8 = *reinterpret_cast<const short8v*>(y + (size_t)dbuf[e] * 256 + 128 + c);
            float r = rbuf[e][0], f0 = rbuf[e][1], f1 = rbuf[e][2];
            float vv[8];
#pragma unroll
            for (int j = 0; j < 8; ++j) {
                float4 q = cmb4[c + j];
                float s = bf2f(a8[j]) + bf2f(b8[j]) + r*q.x + f0*q.y + f1*q.z + q.w;
                vv[j] = silu_f(s);
            }
            uint4 u;
            u.x = pkbf(vv[0], vv[1]); u.y = pkbf(vv[2], vv[3]);
            u.z = pkbf(vv[4], vv[5]); u.w = pkbf(vv[6], vv[7]);
            *reinterpret_cast<uint4*>(&h1buf[e][c]) = u;
        }
    }
    __syncthreads();

    const f32x4 zero = {0.f, 0.f, 0.f, 0.f};
    const short8v* pkv2 = reinterpret_cast<const short8v*>(pk2);
    const short8v* pkv3 = reinterpret_cast<const short8v*>(pk3);

    // ---- GEMM2: K=128 -> silu -> msg ----
    f32x4 acc[2][2];
    acc[0][0] = zero; acc[0][1] = zero; acc[1][0] = zero; acc[1][1] = zero;
    for (int kt = 0; kt < 4; ++kt) {
        short8v b0 = *reinterpret_cast<const short8v*>(&h1buf[(eh << 5) + r16][(kt << 5) + (g << 3)]);
        short8v b1 = *reinterpret_cast<const short8v*>(&h1buf[(eh << 5) + 16 + r16][(kt << 5) + (g << 3)]);
#pragma unroll
        for (int nt = 0; nt < 2; ++nt) {
            short8v a = pkv2[(((kt << 3) + (ch << 1) + nt) << 6) + l];
            acc[0][nt] = __builtin_amdgcn_mfma_f32_16x16x32_bf16(a, b0, acc[0][nt], 0, 0, 0);
            acc[1][nt] = __builtin_amdgcn_mfma_f32_16x16x32_bf16(a, b1, acc[1][nt], 0, 0, 0);
        }
    }
#pragma unroll
    for (int nt = 0; nt < 2; ++nt) {
        int cb = (ch << 5) + (nt << 4) + (g << 2);
        float4 bias = *reinterpret_cast<const float4*>(&eb2[cb]);
#pragma unroll
        for (int et = 0; et < 2; ++et) {
            int e = (eh << 5) + (et << 4) + r16;
            f32x4 v = acc[et][nt];
            uint2 p;
            p.x = pkbf(silu_f(v[0] + bias.x), silu_f(v[1] + bias.y));
            p.y = pkbf(silu_f(v[2] + bias.z), silu_f(v[3] + bias.w));
            *reinterpret_cast<uint2*>(&msgbuf[e][cb]) = p;
        }
    }
    __syncthreads();

    // ---- segmented reduce + flush (dst-sorted runs) ----
    {
        const int c = t & 127;
        const int q = t >> 7;
        float sum = 0.f;
        int cur = dbuf[q << 4];
#pragma unroll
        for (int i = 0; i < 16; ++i) {
            int e = (q << 4) + i;
            sum += __uint_as_float((uint)msgbuf[e][c] << 16);
            int nxt = (i < 15) ? dbuf[e + 1] : -1;
            if (nxt != cur) {
                atomicAdd(&hacc[(size_t)cur * HID + c], sum);
                sum = 0.f; cur = nxt;
            }
        }
    }

    // ---- GEMM3: K=128 -> silu -> dot cW2 ----
    acc[0][0] = zero; acc[0][1] = zero; acc[1][0] = zero; acc[1][1] = zero;
    for (int kt = 0; kt < 4; ++kt) {
        short8v b0 = *reinterpret_cast<const short8v*>(&msgbuf[(eh << 5) + r16][(kt << 5) + (g << 3)]);
        short8v b1 = *reinterpret_cast<const short8v*>(&msgbuf[(eh << 5) + 16 + r16][(kt << 5) + (g << 3)]);
#pragma unroll
        for (int nt = 0; nt < 2; ++nt) {
            short8v a = pkv3[(((kt << 3) + (ch << 1) + nt) << 6) + l];
            acc[0][nt] = __builtin_amdgcn_mfma_f32_16x16x32_bf16(a, b0, acc[0][nt], 0, 0, 0);
            acc[1][nt] = __builtin_amdgcn_mfma_f32_16x16x32_bf16(a, b1, acc[1][nt], 0, 0, 0);
        }
    }
    float part[2] = {0.f, 0.f};
#pragma unroll
    for (int nt = 0; nt < 2; ++nt) {
        int cb = (ch << 5) + (nt << 4) + (g << 2);
        float4 bias = *reinterpret_cast<const float4*>(&cb1[cb]);
        float4 cw   = *reinterpret_cast<const float4*>(&cW2[cb]);
#pragma unroll
        for (int et = 0; et < 2; ++et) {
            f32x4 v = acc[et][nt];
            part[et] += silu_f(v[0] + bias.x) * cw.x + silu_f(v[1] + bias.y) * cw.y
                      + silu_f(v[2] + bias.z) * cw.z + silu_f(v[3] + bias.w) * cw.w;
        }
    }
#pragma unroll
    for (int et = 0; et < 2; ++et) {
        part[et] += __shfl_xor(part[et], 16);
        part[et] += __shfl_xor(part[et], 32);
    }
    if (l < 16) {
        pbuf[ch][(eh << 5) + r16]      = part[0];
        pbuf[ch][(eh << 5) + 16 + r16] = part[1];
    }
    __syncthreads();

    if (t < EPB) {
        float s = pbuf[0][t] + pbuf[1][t] + pbuf[2][t] + pbuf[3][t];
        int gd = dbuf[t];
        atomicAdd(&xacc[(size_t)gd*3 + 0], s * xdbuf[t][0]);
        atomicAdd(&xacc[(size_t)gd*3 + 1], s * xdbuf[t][1]);
        atomicAdd(&xacc[(size_t)gd*3 + 2], s * xdbuf[t][2]);
    }
}

// ---------------------------------------------------------------------------
// OLD edge kernel (r6) — fallback when ws can't hold y.
// ---------------------------------------------------------------------------
template<bool NFB>
__global__ __launch_bounds__(512, 8) void edge_kernel(
    const float* __restrict__ node_feat, const ushort* __restrict__ nfb,
    const float* __restrict__ coord, const float* __restrict__ edge_feat,
    const int* __restrict__ src, const int* __restrict__ dst,
    const int* __restrict__ perm, int use_perm,
    const ushort* __restrict__ pk1, const ushort* __restrict__ pk2,
    const ushort* __restrict__ pk3,
    const float* __restrict__ eb1, const float* __restrict__ eb2,
    const float* __restrict__ cb1, const float* __restrict__ cW2,
    float* __restrict__ hacc, float* __restrict__ xacc)
{
    __shared__ __attribute__((aligned(16))) ushort fbuf[EPB][FP];
    __shared__ int   sbuf[EPB], dbuf[EPB];
    __shared__ float xdbuf[EPB][4];
    __shared__ float pbuf[4][EPB];

    const int t   = threadIdx.x;
    const int l   = t & 63;
    const int w   = t >> 6;
    const int ch  = w & 3;
    const int eh  = w >> 2;
    const int r16 = l & 15;
    const int g   = l >> 4;
    const int e_base = blockIdx.x * EPB;

    int ee = 0;
    if (t < EPB) {
        ee = use_perm ? perm[e_base + t] : (e_base + t);
        sbuf[t] = src[ee];
        dbuf[t] = dst[ee];
    }
    __syncthreads();

    {
        const int e = t >> 3;
        const int c = (t & 7) << 5;
        if (NFB) {
            const ushort* sp = (c < 128) ? nfb + (size_t)sbuf[e] * 128 + c
                                         : nfb + (size_t)dbuf[e] * 128 + (c - 128);
            const short8v* spv = reinterpret_cast<const short8v*>(sp);
#pragma unroll
            for (int i = 0; i < 4; ++i)
                *reinterpret_cast<short8v*>(&fbuf[e][c + (i << 3)]) = spv[i];
        } else {
            const float* sp = (c < 128) ? node_feat + (size_t)sbuf[e] * 128 + c
                                        : node_feat + (size_t)dbuf[e] * 128 + (c - 128);
            const float4* spv = reinterpret_cast<const float4*>(sp);
#pragma unroll
            for (int i = 0; i < 4; ++i) {
                float4 a = spv[2 * i], b = spv[2 * i + 1];
                uint4 u;
                u.x = pkbf(a.x, a.y); u.y = pkbf(a.z, a.w);
                u.z = pkbf(b.x, b.y); u.w = pkbf(b.z, b.w);
                *reinterpret_cast<uint4*>(&fbuf[e][c + (i << 3)]) = u;
            }
        }
    }
    if (t < EPB) {
        const int e = t, s = sbuf[e], d = dbuf[e];
        float dx = coord[(size_t)s*3+0] - coord[(size_t)d*3+0];
        float dy = coord[(size_t)s*3+1] - coord[(size_t)d*3+1];
        float dz = coord[(size_t)s*3+2] - coord[(size_t)d*3+2];
        float radial = dx*dx + dy*dy + dz*dz;
        float inv = 1.0f / (sqrtf(radial) + 1e-30f);
        fbuf[e][256] = f2bf(radial);
        fbuf[e][257] = f2bf(edge_feat[(size_t)ee*2 + 0]);
        fbuf[e][258] = f2bf(edge_feat[(size_t)ee*2 + 1]);
#pragma unroll
        for (int k = 259; k < 288; ++k) fbuf[e][k] = 0;
        xdbuf[e][0] = dx * inv; xdbuf[e][1] = dy * inv; xdbuf[e][2] = dz * inv;
    }
    __syncthreads();

    const f32x4 zero = {0.f, 0.f, 0.f, 0.f};
    const short8v* pkv1 = reinterpret_cast<const short8v*>(pk1);
    const short8v* pkv2 = reinterpret_cast<const short8v*>(pk2);
    const short8v* pkv3 = reinterpret_cast<const short8v*>(pk3);

    f32x4 acc[2][2];
    acc[0][0] = zero; acc[0][1] = zero; acc[1][0] = zero; acc[1][1] = zero;
    for (int kt = 0; kt < 9; ++kt) {
        short8v b0 = *reinterpret_cast<const short8v*>(&fbuf[(eh << 5) + r16][(kt << 5) + (g << 3)]);
        short8v b1 = *reinterpret_cast<const short8v*>(&fbuf[(eh << 5) + 16 + r16][(kt << 5) + (g << 3)]);
#pragma unroll
        for (int nt = 0; nt < 2; ++nt) {
            short8v a = pkv1[(((kt << 3) + (ch << 1) + nt) << 6) + l];
            acc[0][nt] = __builtin_amdgcn_mfma_f32_16x16x32_bf16(a, b0, acc[0][nt], 0, 0, 0);
            acc[1][nt] = __builtin_amdgcn_mfma_f32_16x16x32_bf16(a, b1, acc[1][nt], 0, 0, 0);
        }
    }
    __syncthreads();
#pragma unroll
    for (int nt = 0; nt < 2; ++nt) {
        int cb = (ch << 5) + (nt << 4) + (g << 2);
        float4 bias = *reinterpret_cast<const float4*>(&eb1[cb]);
#pragma unroll
        for (int et = 0; et < 2; ++et) {
            int e = (eh << 5) + (et << 4) + r16;
            f32x4 v = acc[et][nt];
            uint2 p;
            p.x = pkbf(silu_f(v[0] + bias.x), silu_f(v[1] + bias.y));
            p.y = pkbf(silu_f(v[2] + bias.z), silu_f(v[3] + bias.w));
            *reinterpret_cast<uint2*>(&fbuf[e][H1OFF + cb]) = p;
        }
    }
    __syncthreads();

    acc[0][0] = zero; acc[0][1] = zero; acc[1][0] = zero; acc[1][1] = zero;
    for (int kt = 0; kt < 4; ++kt) {
        short8v b0 = *reinterpret_cast<const short8v*>(&fbuf[(eh << 5) + r16][H1OFF + (kt << 5) + (g << 3)]);
        short8v b1 = *reinterpret_cast<const short8v*>(&fbuf[(eh << 5) + 16 + r16][H1OFF + (kt << 5) + (g << 3)]);
#pragma unroll
        for (int nt = 0; nt < 2; ++nt) {
            short8v a = pkv2[(((kt << 3) + (ch << 1) + nt) << 6) + l];
            acc[0][nt] = __builtin_amdgcn_mfma_f32_16x16x32_bf16(a, b0, acc[0][nt], 0, 0, 0);
            acc[1][nt] = __builtin_amdgcn_mfma_f32_16x16x32_bf16(a, b1, acc[1][nt], 0, 0, 0);
        }
    }
#pragma unroll
    for (int nt = 0; nt < 2; ++nt) {
        int cb = (ch << 5) + (nt << 4) + (g << 2);
        float4 bias = *reinterpret_cast<const float4*>(&eb2[cb]);
#pragma unroll
        for (int et = 0; et < 2; ++et) {
            int e = (eh << 5) + (et << 4) + r16;
            f32x4 v = acc[et][nt];
            uint2 p;
            p.x = pkbf(silu_f(v[0] + bias.x), silu_f(v[1] + bias.y));
            p.y = pkbf(silu_f(v[2] + bias.z), silu_f(v[3] + bias.w));
            *reinterpret_cast<uint2*>(&fbuf[e][cb]) = p;
        }
    }
    __syncthreads();

    {
        const int c = t & 127;
        const int q = t >> 7;
        float sum = 0.f;
        int cur = dbuf[q << 4];
#pragma unroll
        for (int i = 0; i < 16; ++i) {
            int e = (q << 4) + i;
            sum += __uint_as_float((uint)fbuf[e][c] << 16);
            int nxt = (i < 15) ? dbuf[e + 1] : -1;
            if (nxt != cur) {
                atomicAdd(&hacc[(size_t)cur * HID + c], sum);
                sum = 0.f; cur = nxt;
            }
        }
    }

    acc[0][0] = zero; acc[0][1] = zero; acc[1][0] = zero; acc[1][1] = zero;
    for (int kt = 0; kt < 4; ++kt) {
        short8v b0 = *reinterpret_cast<const short8v*>(&fbuf[(eh << 5) + r16][(kt << 5) + (g << 3)]);
        short8v b1 = *reinterpret_cast<const short8v*>(&fbuf[(eh << 5) + 16 + r16][(kt << 5) + (g << 3)]);
#pragma unroll
        for (int nt = 0; nt < 2; ++nt) {
            short8v a = pkv3[(((kt << 3) + (ch << 1) + nt) << 6) + l];
            acc[0][nt] = __builtin_amdgcn_mfma_f32_16x16x32_bf16(a, b0, acc[0][nt], 0, 0, 0);
            acc[1][nt] = __builtin_amdgcn_mfma_f32_16x16x32_bf16(a, b1, acc[1][nt], 0, 0, 0);
        }
    }
    float part[2] = {0.f, 0.f};
#pragma unroll
    for (int nt = 0; nt < 2; ++nt) {
        int cb = (ch << 5) + (nt << 4) + (g << 2);
        float4 bias = *reinterpret_cast<const float4*>(&cb1[cb]);
        float4 cw   = *reinterpret_cast<const float4*>(&cW2[cb]);
#pragma unroll
        for (int et = 0; et < 2; ++et) {
            f32x4 v = acc[et][nt];
            part[et] += silu_f(v[0] + bias.x) * cw.x + silu_f(v[1] + bias.y) * cw.y
                      + silu_f(v[2] + bias.z) * cw.z + silu_f(v[3] + bias.w) * cw.w;
        }
    }
#pragma unroll
    for (int et = 0; et < 2; ++et) {
        part[et] += __shfl_xor(part[et], 16);
        part[et] += __shfl_xor(part[et], 32);
    }
    if (l < 16) {
        pbuf[ch][(eh << 5) + r16]      = part[0];
        pbuf[ch][(eh << 5) + 16 + r16] = part[1];
    }
    __syncthreads();

    if (t < EPB) {
        float s = pbuf[0][t] + pbuf[1][t] + pbuf[2][t] + pbuf[3][t];
        int gd = dbuf[t];
        atomicAdd(&xacc[(size_t)gd*3 + 0], s * xdbuf[t][0]);
        atomicAdd(&xacc[(size_t)gd*3 + 1], s * xdbuf[t][1]);
        atomicAdd(&xacc[(size_t)gd*3 + 2], s * xdbuf[t][2]);
    }
}

// ---------------------------------------------------------------------------
// Node kernel (MFMA): 256 thr = 4 waves, 32 nodes/block. deg from CSR ptr.
// ---------------------------------------------------------------------------
template<bool NFB>
__global__ __launch_bounds__(256) void node_kernel(
    const float* __restrict__ node_feat, const ushort* __restrict__ nfb,
    const float* __restrict__ coord,
    const ushort* __restrict__ pkn1, const ushort* __restrict__ pkn2,
    const float* __restrict__ nb1, const float* __restrict__ nb2,
    float* __restrict__ dout, const int* __restrict__ ptr)
{
    __shared__ __attribute__((aligned(16))) ushort catb[32][CP];
    __shared__ __attribute__((aligned(16))) ushort h1b[32][HP];

    const int t   = threadIdx.x;
    const int l   = t & 63;
    const int w   = t >> 6;
    const int ch  = w & 1;
    const int eh  = w >> 1;
    const int r16 = l & 15;
    const int g   = l >> 4;
    const int nb  = blockIdx.x * 32;

    {
        int nd = t >> 3;
        int c  = (t & 7) << 5;
        int gn = nb + nd; if (gn >= N_NODES) gn = N_NODES - 1;
        if (c < 128) {
            if (NFB) {
                const short8v* spv = reinterpret_cast<const short8v*>(nfb + (size_t)gn * 128 + c);
#pragma unroll
                for (int i = 0; i < 4; ++i)
                    *reinterpret_cast<short8v*>(&catb[nd][c + (i << 3)]) = spv[i];
            } else {
                const float4* spv = reinterpret_cast<const float4*>(node_feat + (size_t)gn * 128 + c);
#pragma unroll
                for (int i = 0; i < 4; ++i) {
                    float4 a = spv[2 * i], b = spv[2 * i + 1];
                    uint4 u;
                    u.x = pkbf(a.x, a.y); u.y = pkbf(a.z, a.w);
                    u.z = pkbf(b.x, b.y); u.w = pkbf(b.z, b.w);
                    *reinterpret_cast<uint4*>(&catb[nd][c + (i << 3)]) = u;
                }
            }
        } else {
            const float4* spv = reinterpret_cast<const float4*>(dout + (size_t)gn * HID + (c - 128));
#pragma unroll
            for (int i = 0; i < 4; ++i) {
                float4 a = spv[2 * i], b = spv[2 * i + 1];
                uint4 u;
                u.x = pkbf(a.x, a.y); u.y = pkbf(a.z, a.w);
                u.z = pkbf(b.x, b.y); u.w = pkbf(b.z, b.w);
                *reinterpret_cast<uint4*>(&catb[nd][c + (i << 3)]) = u;
            }
        }
    }
    __syncthreads();

    const f32x4 zero = {0.f, 0.f, 0.f, 0.f};
    const short8v* pv1 = reinterpret_cast<const short8v*>(pkn1);
    const short8v* pv2 = reinterpret_cast<const short8v*>(pkn2);

    f32x4 acc[4];
#pragma unroll
    for (int nt = 0; nt < 4; ++nt) acc[nt] = zero;
    for (int kt = 0; kt < 8; ++kt) {
        short8v b = *reinterpret_cast<const short8v*>(&catb[(eh << 4) + r16][(kt << 5) + (g << 3)]);
#pragma unroll
        for (int nt = 0; nt < 4; ++nt) {
            short8v a = pv1[(((kt << 3) + (ch << 2) + nt) << 6) + l];
            acc[nt] = __builtin_amdgcn_mfma_f32_16x16x32_bf16(a, b, acc[nt], 0, 0, 0);
        }
    }
#pragma unroll
    for (int nt = 0; nt < 4; ++nt) {
        int cb = (ch << 6) + (nt << 4) + (g << 2);
        float4 bias = *reinterpret_cast<const float4*>(&nb1[cb]);
        int nd = (eh << 4) + r16;
        f32x4 v = acc[nt];
        uint2 p;
        p.x = pkbf(silu_f(v[0] + bias.x), silu_f(v[1] + bias.y));
        p.y = pkbf(silu_f(v[2] + bias.z), silu_f(v[3] + bias.w));
        *reinterpret_cast<uint2*>(&h1b[nd][cb]) = p;
    }
    __syncthreads();

#pragma unroll
    for (int nt = 0; nt < 4; ++nt) acc[nt] = zero;
    for (int kt = 0; kt < 4; ++kt) {
        short8v b = *reinterpret_cast<const short8v*>(&h1b[(eh << 4) + r16][(kt << 5) + (g << 3)]);
#pragma unroll
        for (int nt = 0; nt < 4; ++nt) {
            short8v a = pv2[(((kt << 3) + (ch << 2) + nt) << 6) + l];
            acc[nt] = __builtin_amdgcn_mfma_f32_16x16x32_bf16(a, b, acc[nt], 0, 0, 0);
        }
    }
    {
        int gw = nb + (eh << 4) + r16;
        if (gw < N_NODES) {
#pragma unroll
            for (int nt = 0; nt < 4; ++nt) {
                int cb = (ch << 6) + (nt << 4) + (g << 2);
                float4 bias = *reinterpret_cast<const float4*>(&nb2[cb]);
                f32x4 v = acc[nt];
                float4 o;
                o.x = v[0] + bias.x; o.y = v[1] + bias.y;
                o.z = v[2] + bias.z; o.w = v[3] + bias.w;
                *reinterpret_cast<float4*>(&dout[(size_t)gw * HID + cb]) = o;
            }
        }
    }

    if (t < 96) {
        int nd = t / 3, d = t - 3 * nd;
        int gn = nb + nd;
        if (gn < N_NODES) {
            size_t xi = XOFF + (size_t)gn * 3 + d;
            float dg = (float)(ptr[gn + 1] - ptr[gn]);
            dg = dg > 1.0f ? dg : 1.0f;
            dout[xi] = coord[(size_t)gn * 3 + d] + dout[xi] / dg;
        }
    }
}

extern "C" void kernel_launch(void* const* d_in, const int* in_sizes, int n_in,
                              void* d_out, int out_size, void* d_ws, size_t ws_size,
                              hipStream_t stream) {
    const float* node_feat = (const float*)d_in[0];
    const float* coord     = (const float*)d_in[1];
    const float* edge_feat = (const float*)d_in[2];
    const int*   src       = (const int*)d_in[3];
    const int*   dst       = (const int*)d_in[4];
    const float* eW1 = (const float*)d_in[5];
    const float* eb1 = (const float*)d_in[6];
    const float* eW2 = (const float*)d_in[7];
    const float* eb2 = (const float*)d_in[8];
    const float* nW1 = (const float*)d_in[9];
    const float* nb1 = (const float*)d_in[10];
    const float* nW2 = (const float*)d_in[11];
    const float* nb2 = (const float*)d_in[12];
    const float* cW1 = (const float*)d_in[13];
    const float* cb1 = (const float*)d_in[14];
    const float* cW2 = (const float*)d_in[15];

    float* out = (float*)d_out;
    char* base = (char*)d_ws;
    // ws layout (bytes):
    int*    ptrb   = (int*)base;                      // 0       .. 200064
    int*    part   = (int*)(base + 200064);           // 200064  .. 200320
    int*    ptr2   = (int*)(base + 200320);           // 200320  .. 400384
    ushort* pk1old = (ushort*)(base + 400384);        // 400384  .. 474112
    ushort* pka    = (ushort*)(base + 474112);        // 474112  .. 506880
    ushort* pkb    = (ushort*)(base + 506880);        // 506880  .. 539648
    ushort* pk2    = (ushort*)(base + 539648);        // 539648  .. 572416
    ushort* pk3    = (ushort*)(base + 572416);        // 572416  .. 605184
    ushort* pkn1   = (ushort*)(base + 605184);        // 605184  .. 670720
    ushort* pkn2   = (ushort*)(base + 670720);        // 670720  .. 703488
    float*  cmb    = (float*)(base + 703488);         // 703488  .. 705536
    int*    perm   = (int*)(base + 705536);           // 705536  .. 3905536
    ushort* ybuf   = (ushort*)(base + 3905536);       // y: +25.6MB | nfb: +12.8MB
    const size_t need_y    = 3905536 + (size_t)N_NODES * 256 * 2;   // 29505536
    const size_t need_nfb  = 3905536 + (size_t)N_NODES * 128 * 2;   // 16705536
    const size_t need_perm = 3905536;
    const bool use_y    = ws_size >= need_y;
    const bool use_nfb  = !use_y && ws_size >= need_nfb;
    const bool use_perm = ws_size >= need_perm;

    hipMemsetAsync(d_out, 0, (size_t)out_size * sizeof(float), stream);
    hipMemsetAsync(d_ws, 0, 200064, stream);

    int prep_grid = (use_nfb ? (19072 + N_NODES * 16) + 255 : 19072 + 255) / 256;
    prep_kernel<<<prep_grid, 256, 0, stream>>>(
        eW1, eW2, cW1, nW1, nW2, eb1, node_feat,
        pk1old, pka, pkb, pk2, pk3, pkn1, pkn2, cmb, ybuf, use_nfb ? 1 : 0);

    hist_kernel<<<(E_TOTAL + 255) / 256, 256, 0, stream>>>(dst, ptrb);
    scan_a<<<49, 1024, 0, stream>>>(ptrb, part);
    scan_b<<<1, 64, 0, stream>>>(part, 49);
    scan_c<<<49, 1024, 0, stream>>>(ptrb, part, ptr2);
    if (use_perm)
        scatter_kernel<<<(E_TOTAL + 255) / 256, 256, 0, stream>>>(dst, ptr2, perm);

    if (use_y) {
        ygemm_kernel<<<(N_NODES + 31) / 32, 256, 0, stream>>>(node_feat, pka, pkb, ybuf);
        edge2_kernel<<<E_TOTAL / EPB, 512, 0, stream>>>(
            ybuf, coord, edge_feat, src, dst, perm, cmb,
            pk2, pk3, eb2, cb1, cW2, out, out + XOFF);
        node_kernel<false><<<(N_NODES + 31) / 32, 256, 0, stream>>>(
            node_feat, ybuf, coord, pkn1, pkn2, nb1, nb2, out, ptrb);
    } else if (use_nfb) {
        edge_kernel<true><<<E_TOTAL / EPB, 512, 0, stream>>>(
            node_feat, ybuf, coord, edge_feat, src, dst, perm, use_perm ? 1 : 0,
            pk1old, pk2, pk3, eb1, eb2, cb1, cW2, out, out + XOFF);
        node_kernel<true><<<(N_NODES + 31) / 32, 256, 0, stream>>>(
            node_feat, ybuf, coord, pkn1, pkn2, nb1, nb2, out, ptrb);
    } else {
        edge_kernel<false><<<E_TOTAL / EPB, 512, 0, stream>>>(
            node_feat, ybuf, coord, edge_feat, src, dst, perm, use_perm ? 1 : 0,
            pk1old, pk2, pk3, eb1, eb2, cb1, cW2, out, out + XOFF);
        node_kernel<false><<<(N_NODES + 31) / 32, 256, 0, stream>>>(
            node_feat, ybuf, coord, pkn1, pkn2, nb1, nb2, out, ptrb);
    }
}

// Round 13
// 513.780 us; speedup vs baseline: 1.1862x; 1.0180x over previous
//
#include <hip/hip_runtime.h>
#include <hip/hip_bf16.h>

#define N_NODES 50000
#define E_TOTAL 800000
#define IN      128
#define HID     128
#define EPB     64
#define XOFF    ((size_t)N_NODES * HID)
#define FP      296     // old-path fbuf pitch
#define H1OFF   160
#define HP      136
#define CP      264

typedef __attribute__((ext_vector_type(8))) short short8v;
typedef __attribute__((ext_vector_type(4))) float f32x4;

__device__ __forceinline__ float silu_f(float x) { return x / (1.0f + __expf(-x)); }

__device__ __forceinline__ uint pkbf(float lo, float hi) {
    float2 f; f.x = lo; f.y = hi;
    __hip_bfloat162 h = __float22bfloat162_rn(f);
    union { __hip_bfloat162 h; uint u; } c; c.h = h;
    return c.u;
}

__device__ __forceinline__ ushort f2bf(float x) {
    uint u = __float_as_uint(x);
    u += 0x7fff + ((u >> 16) & 1);
    return (ushort)(u >> 16);
}

__device__ __forceinline__ float bf2f(short s) {
    return __uint_as_float(((uint)(ushort)s) << 16);
}

// ---------------------------------------------------------------------------
// prep (+hist +nfb): pack weights into MFMA fragment order (entry (kt,n,l)[j] =
// W[kt*32+8*(l>>4)+j][n*16+(l&15)]); cmb table; dst histogram; node_feat->bf16.
// ids: 0..18943 weights | 18944..19071 cmb | 19200..19200+E hist | then nfb.
// ---------------------------------------------------------------------------
__global__ __launch_bounds__(256) void prep_kernel(
    const float* __restrict__ eW1, const float* __restrict__ eW2,
    const float* __restrict__ cW1, const float* __restrict__ nW1,
    const float* __restrict__ nW2, const float* __restrict__ eb1,
    const float* __restrict__ node_feat,
    const int* __restrict__ dst, int* __restrict__ cnt,
    ushort* __restrict__ pk1old, ushort* __restrict__ pka, ushort* __restrict__ pkb,
    ushort* __restrict__ pk2, ushort* __restrict__ pk3,
    ushort* __restrict__ pkn1, ushort* __restrict__ pkn2,
    float* __restrict__ cmb, ushort* __restrict__ nfb, int do_nfb)
{
    int id = blockIdx.x * 256 + threadIdx.x;
    if (id < 18944) {
        const float* W; ushort* dp; int K, idx;
        if (id < 4608)       { idx = id;         W = eW1;            dp = pk1old; K = 259; }
        else if (id < 6656)  { idx = id - 4608;  W = eW1;            dp = pka;    K = 128; }
        else if (id < 8704)  { idx = id - 6656;  W = eW1 + 128*128;  dp = pkb;    K = 128; }
        else if (id < 10752) { idx = id - 8704;  W = eW2;            dp = pk2;    K = 128; }
        else if (id < 12800) { idx = id - 10752; W = cW1;            dp = pk3;    K = 128; }
        else if (id < 16896) { idx = id - 12800; W = nW1;            dp = pkn1;   K = 256; }
        else                 { idx = id - 16896; W = nW2;            dp = pkn2;   K = 128; }
        int kt = idx >> 9, n = (idx >> 6) & 7, ll = idx & 63;
        int col = (n << 4) + (ll & 15);
        short8v o;
#pragma unroll
        for (int j = 0; j < 8; ++j) {
            int k = (kt << 5) + ((ll >> 4) << 3) + j;
            o[j] = (k < K) ? (short)f2bf(W[(size_t)k * 128 + col]) : (short)0;
        }
        *reinterpret_cast<short8v*>(dp + (size_t)idx * 8) = o;
    } else if (id < 19072) {
        int c = id - 18944;
        cmb[c*4+0] = eW1[256*128 + c];
        cmb[c*4+1] = eW1[257*128 + c];
        cmb[c*4+2] = eW1[258*128 + c];
        cmb[c*4+3] = eb1[c];
    } else if (id < 19200) {
        // pad
    } else if (id < 19200 + E_TOTAL) {
        int e = id - 19200;
        atomicAdd(&cnt[dst[e]], 1);
    } else if (do_nfb) {
        int idx = id - 19200 - E_TOTAL;
        if (idx < N_NODES * 16) {
            const float4* s = reinterpret_cast<const float4*>(node_feat + (size_t)idx * 8);
            float4 a = s[0], b = s[1];
            uint4 u;
            u.x = pkbf(a.x, a.y); u.y = pkbf(a.z, a.w);
            u.z = pkbf(b.x, b.y); u.w = pkbf(b.z, b.w);
            *reinterpret_cast<uint4*>(nfb + (size_t)idx * 8) = u;
        }
    }
}

// ---------------------------------------------------------------------------
// CSR build: scan_a (block sums) -> scan_c2 (in-block partial scan + apply)
// -> scatter permutation.
// ---------------------------------------------------------------------------
__global__ __launch_bounds__(1024) void scan_a(
    const int* __restrict__ cnt, int* __restrict__ part)
{
    __shared__ int ws[16];
    int t = threadIdx.x, lane = t & 63, wv = t >> 6;
    int i = blockIdx.x * 1024 + t;
    int v = (i < N_NODES) ? cnt[i] : 0;
#pragma unroll
    for (int off = 32; off >= 1; off >>= 1) v += __shfl_xor(v, off);
    if (lane == 0) ws[wv] = v;
    __syncthreads();
    if (t < 16) {
        int s = ws[t];
#pragma unroll
        for (int off = 8; off >= 1; off >>= 1) s += __shfl_xor(s, off);
        if (t == 0) part[blockIdx.x] = s;
    }
}

__global__ __launch_bounds__(1024) void scan_c2(
    int* __restrict__ cnt, const int* __restrict__ part, int* __restrict__ ptr2)
{
    __shared__ int ws[16];
    __shared__ int base_s;
    int t = threadIdx.x, lane = t & 63, wv = t >> 6;

    // phase 0: wave 0 scans the 49 partials, extracts prefix for this block
    if (t < 64) {
        int pv = (t < 49) ? part[t] : 0;
        int px = pv;
#pragma unroll
        for (int off = 1; off < 64; off <<= 1) {
            int y = __shfl_up(px, off);
            if (t >= off) px += y;
        }
        int b = blockIdx.x;
        if (b == 0) { if (t == 0) base_s = 0; }
        else        { if (t == b - 1) base_s = px; }
    }

    int i = blockIdx.x * 1024 + t;
    int v = (i < N_NODES) ? cnt[i] : 0;
    int x = v;
#pragma unroll
    for (int off = 1; off < 64; off <<= 1) {
        int y = __shfl_up(x, off);
        if (lane >= off) x += y;
    }
    if (lane == 63) ws[wv] = x;
    __syncthreads();
    if (t < 16) {
        int s = ws[t], xx = s;
#pragma unroll
        for (int off = 1; off < 16; off <<= 1) {
            int y = __shfl_up(xx, off);
            if (t >= off) xx += y;
        }
        ws[t] = xx - s;
    }
    __syncthreads();
    int excl = base_s + ws[wv] + x - v;
    if (i < N_NODES) { cnt[i] = excl; ptr2[i] = excl; }
    if (i == N_NODES - 1) { cnt[N_NODES] = E_TOTAL; ptr2[N_NODES] = E_TOTAL; }
}

__global__ __launch_bounds__(256) void scatter_kernel(
    const int* __restrict__ dst, int* __restrict__ ptr2, int* __restrict__ perm)
{
    int e = blockIdx.x * 256 + threadIdx.x;
    if (e < E_TOTAL) {
        int p = atomicAdd(&ptr2[dst[e]], 1);
        perm[p] = e;
    }
}

// ---------------------------------------------------------------------------
// ygemm: y[n][0:128] = h[n] @ eW1[0:128]; y[n][128:256] = h[n] @ eW1[128:256].
// 256 thr = 4 waves, 32 nodes/block. A=weight frags, B=node frags.
// ---------------------------------------------------------------------------
__global__ __launch_bounds__(256) void ygemm_kernel(
    const float* __restrict__ node_feat,
    const ushort* __restrict__ pka, const ushort* __restrict__ pkb,
    ushort* __restrict__ y)
{
    __shared__ __attribute__((aligned(16))) ushort catb[32][HP];
    __shared__ __attribute__((aligned(16))) ushort ybuf[32][CP];

    const int t   = threadIdx.x;
    const int l   = t & 63;
    const int ch  = t >> 6;        // wave 0..3 -> y cols ch*64..+63
    const int r16 = l & 15;
    const int g   = l >> 4;
    const int nb  = blockIdx.x * 32;

    {   // stage 32 nodes x 128 chans bf16
        int nd = t >> 3;
        int c  = (t & 7) << 4;
        int gn = nb + nd; if (gn >= N_NODES) gn = N_NODES - 1;
        const float4* sp = reinterpret_cast<const float4*>(node_feat + (size_t)gn * 128 + c);
        float4 a = sp[0], b = sp[1], cc = sp[2], dd = sp[3];
        uint4 u0, u1;
        u0.x = pkbf(a.x, a.y);  u0.y = pkbf(a.z, a.w);
        u0.z = pkbf(b.x, b.y);  u0.w = pkbf(b.z, b.w);
        u1.x = pkbf(cc.x, cc.y); u1.y = pkbf(cc.z, cc.w);
        u1.z = pkbf(dd.x, dd.y); u1.w = pkbf(dd.z, dd.w);
        *reinterpret_cast<uint4*>(&catb[nd][c])     = u0;
        *reinterpret_cast<uint4*>(&catb[nd][c + 8]) = u1;
    }
    __syncthreads();

    const f32x4 zero = {0.f, 0.f, 0.f, 0.f};
    const short8v* pa = reinterpret_cast<const short8v*>((ch < 2) ? pka : pkb);
    const int nbase = (ch & 1) << 2;

    f32x4 acc[2][4];
#pragma unroll
    for (int et = 0; et < 2; ++et)
#pragma unroll
        for (int nt = 0; nt < 4; ++nt) acc[et][nt] = zero;

    for (int kt = 0; kt < 4; ++kt) {
        short8v b0 = *reinterpret_cast<const short8v*>(&catb[r16][(kt << 5) + (g << 3)]);
        short8v b1 = *reinterpret_cast<const short8v*>(&catb[16 + r16][(kt << 5) + (g << 3)]);
#pragma unroll
        for (int nt = 0; nt < 4; ++nt) {
            short8v a = pa[(((kt << 3) + nbase + nt) << 6) + l];
            acc[0][nt] = __builtin_amdgcn_mfma_f32_16x16x32_bf16(a, b0, acc[0][nt], 0, 0, 0);
            acc[1][nt] = __builtin_amdgcn_mfma_f32_16x16x32_bf16(a, b1, acc[1][nt], 0, 0, 0);
        }
    }
#pragma unroll
    for (int nt = 0; nt < 4; ++nt) {
        int cb = (ch << 6) + (nt << 4) + (g << 2);
#pragma unroll
        for (int et = 0; et < 2; ++et) {
            f32x4 v = acc[et][nt];
            uint2 p;
            p.x = pkbf(v[0], v[1]); p.y = pkbf(v[2], v[3]);
            *reinterpret_cast<uint2*>(&ybuf[(et << 4) + r16][cb]) = p;
        }
    }
    __syncthreads();

#pragma unroll
    for (int i = 0; i < 4; ++i) {
        int idx = t + (i << 8);
        int nd  = idx >> 5;
        int c16 = (idx & 31) << 3;
        int gn  = nb + nd;
        if (gn < N_NODES)
            *reinterpret_cast<short8v*>(y + (size_t)gn * 256 + c16) =
                *reinterpret_cast<const short8v*>(&ybuf[nd][c16]);
    }
}

// ---------------------------------------------------------------------------
// NEW edge kernel: no GEMM1. h1 = silu(ya[src]+yb[dst]+r*wr+ef·We+b).
// 512 thr = 8 waves, EPB=64 dst-sorted edges.
// ---------------------------------------------------------------------------
__global__ __launch_bounds__(512, 4) void edge2_kernel(
    const ushort* __restrict__ y, const float* __restrict__ coord,
    const float* __restrict__ edge_feat,
    const int* __restrict__ src, const int* __restrict__ dst,
    const int* __restrict__ perm,
    const float* __restrict__ cmb,
    const ushort* __restrict__ pk2, const ushort* __restrict__ pk3,
    const float* __restrict__ eb2,
    const float* __restrict__ cb1, const float* __restrict__ cW2,
    float* __restrict__ hacc, float* __restrict__ xacc)
{
    __shared__ __attribute__((aligned(16))) ushort h1buf[EPB][HP];
    __shared__ __attribute__((aligned(16))) ushort msgbuf[EPB][HP];
    __shared__ int   sbuf[EPB], dbuf[EPB];
    __shared__ float xdbuf[EPB][4];
    __shared__ float rbuf[EPB][4];
    __shared__ float pbuf[4][EPB];

    const int t   = threadIdx.x;
    const int l   = t & 63;
    const int w   = t >> 6;
    const int ch  = w & 3;
    const int eh  = w >> 2;
    const int r16 = l & 15;
    const int g   = l >> 4;
    const int e_base = blockIdx.x * EPB;

    if (t < EPB) {
        int ee = perm[e_base + t];
        int s = src[ee], d = dst[ee];
        sbuf[t] = s; dbuf[t] = d;
        float dx = coord[(size_t)s*3+0] - coord[(size_t)d*3+0];
        float dy = coord[(size_t)s*3+1] - coord[(size_t)d*3+1];
        float dz = coord[(size_t)s*3+2] - coord[(size_t)d*3+2];
        float radial = dx*dx + dy*dy + dz*dz;
        float inv = 1.0f / (sqrtf(radial) + 1e-30f);
        xdbuf[t][0] = dx * inv; xdbuf[t][1] = dy * inv; xdbuf[t][2] = dz * inv;
        rbuf[t][0] = radial;
        rbuf[t][1] = edge_feat[(size_t)ee*2 + 0];
        rbuf[t][2] = edge_feat[(size_t)ee*2 + 1];
    }
    __syncthreads();

    // ---- gather-combine -> h1 ----
    {
        const int c = (t & 15) << 3;
        const float4* cmb4 = reinterpret_cast<const float4*>(cmb);
#pragma unroll
        for (int p = 0; p < 2; ++p) {
            int e = (t >> 4) + (p << 5);
            short8v a8 = *reinterpret_cast<const short8v*>(y + (size_t)sbuf[e] * 256 + c);
            short8v b8 = *reinterpret_cast<const short8v*>(y + (size_t)dbuf[e] * 256 + 128 + c);
            float r = rbuf[e][0], f0 = rbuf[e][1], f1 = rbuf[e][2];
            float vv[8];
#pragma unroll
            for (int j = 0; j < 8; ++j) {
                float4 q = cmb4[c + j];
                float s = bf2f(a8[j]) + bf2f(b8[j]) + r*q.x + f0*q.y + f1*q.z + q.w;
                vv[j] = silu_f(s);
            }
            uint4 u;
            u.x = pkbf(vv[0], vv[1]); u.y = pkbf(vv[2], vv[3]);
            u.z = pkbf(vv[4], vv[5]); u.w = pkbf(vv[6], vv[7]);
            *reinterpret_cast<uint4*>(&h1buf[e][c]) = u;
        }
    }
    __syncthreads();

    const f32x4 zero = {0.f, 0.f, 0.f, 0.f};
    const short8v* pkv2 = reinterpret_cast<const short8v*>(pk2);
    const short8v* pkv3 = reinterpret_cast<const short8v*>(pk3);

    // ---- GEMM2: K=128 -> silu -> msg ----
    f32x4 acc[2][2];
    acc[0][0] = zero; acc[0][1] = zero; acc[1][0] = zero; acc[1][1] = zero;
    for (int kt = 0; kt < 4; ++kt) {
        short8v b0 = *reinterpret_cast<const short8v*>(&h1buf[(eh << 5) + r16][(kt << 5) + (g << 3)]);
        short8v b1 = *reinterpret_cast<const short8v*>(&h1buf[(eh << 5) + 16 + r16][(kt << 5) + (g << 3)]);
#pragma unroll
        for (int nt = 0; nt < 2; ++nt) {
            short8v a = pkv2[(((kt << 3) + (ch << 1) + nt) << 6) + l];
            acc[0][nt] = __builtin_amdgcn_mfma_f32_16x16x32_bf16(a, b0, acc[0][nt], 0, 0, 0);
            acc[1][nt] = __builtin_amdgcn_mfma_f32_16x16x32_bf16(a, b1, acc[1][nt], 0, 0, 0);
        }
    }
#pragma unroll
    for (int nt = 0; nt < 2; ++nt) {
        int cb = (ch << 5) + (nt << 4) + (g << 2);
        float4 bias = *reinterpret_cast<const float4*>(&eb2[cb]);
#pragma unroll
        for (int et = 0; et < 2; ++et) {
            int e = (eh << 5) + (et << 4) + r16;
            f32x4 v = acc[et][nt];
            uint2 p;
            p.x = pkbf(silu_f(v[0] + bias.x), silu_f(v[1] + bias.y));
            p.y = pkbf(silu_f(v[2] + bias.z), silu_f(v[3] + bias.w));
            *reinterpret_cast<uint2*>(&msgbuf[e][cb]) = p;
        }
    }
    __syncthreads();

    // ---- segmented reduce + flush (dst-sorted runs) ----
    {
        const int c = t & 127;
        const int q = t >> 7;
        float sum = 0.f;
        int cur = dbuf[q << 4];
#pragma unroll
        for (int i = 0; i < 16; ++i) {
            int e = (q << 4) + i;
            sum += __uint_as_float((uint)msgbuf[e][c] << 16);
            int nxt = (i < 15) ? dbuf[e + 1] : -1;
            if (nxt != cur) {
                atomicAdd(&hacc[(size_t)cur * HID + c], sum);
                sum = 0.f; cur = nxt;
            }
        }
    }

    // ---- GEMM3: K=128 -> silu -> dot cW2 ----
    acc[0][0] = zero; acc[0][1] = zero; acc[1][0] = zero; acc[1][1] = zero;
    for (int kt = 0; kt < 4; ++kt) {
        short8v b0 = *reinterpret_cast<const short8v*>(&msgbuf[(eh << 5) + r16][(kt << 5) + (g << 3)]);
        short8v b1 = *reinterpret_cast<const short8v*>(&msgbuf[(eh << 5) + 16 + r16][(kt << 5) + (g << 3)]);
#pragma unroll
        for (int nt = 0; nt < 2; ++nt) {
            short8v a = pkv3[(((kt << 3) + (ch << 1) + nt) << 6) + l];
            acc[0][nt] = __builtin_amdgcn_mfma_f32_16x16x32_bf16(a, b0, acc[0][nt], 0, 0, 0);
            acc[1][nt] = __builtin_amdgcn_mfma_f32_16x16x32_bf16(a, b1, acc[1][nt], 0, 0, 0);
        }
    }
    float part[2] = {0.f, 0.f};
#pragma unroll
    for (int nt = 0; nt < 2; ++nt) {
        int cb = (ch << 5) + (nt << 4) + (g << 2);
        float4 bias = *reinterpret_cast<const float4*>(&cb1[cb]);
        float4 cw   = *reinterpret_cast<const float4*>(&cW2[cb]);
#pragma unroll
        for (int et = 0; et < 2; ++et) {
            f32x4 v = acc[et][nt];
            part[et] += silu_f(v[0] + bias.x) * cw.x + silu_f(v[1] + bias.y) * cw.y
                      + silu_f(v[2] + bias.z) * cw.z + silu_f(v[3] + bias.w) * cw.w;
        }
    }
#pragma unroll
    for (int et = 0; et < 2; ++et) {
        part[et] += __shfl_xor(part[et], 16);
        part[et] += __shfl_xor(part[et], 32);
    }
    if (l < 16) {
        pbuf[ch][(eh << 5) + r16]      = part[0];
        pbuf[ch][(eh << 5) + 16 + r16] = part[1];
    }
    __syncthreads();

    if (t < EPB) {
        float s = pbuf[0][t] + pbuf[1][t] + pbuf[2][t] + pbuf[3][t];
        int gd = dbuf[t];
        atomicAdd(&xacc[(size_t)gd*3 + 0], s * xdbuf[t][0]);
        atomicAdd(&xacc[(size_t)gd*3 + 1], s * xdbuf[t][1]);
        atomicAdd(&xacc[(size_t)gd*3 + 2], s * xdbuf[t][2]);
    }
}

// ---------------------------------------------------------------------------
// Node kernel (MFMA): 256 thr = 4 waves, 32 nodes/block. deg from CSR ptr.
// ---------------------------------------------------------------------------
template<bool NFB>
__global__ __launch_bounds__(256) void node_kernel(
    const float* __restrict__ node_feat, const ushort* __restrict__ nfb,
    const float* __restrict__ coord,
    const ushort* __restrict__ pkn1, const ushort* __restrict__ pkn2,
    const float* __restrict__ nb1, const float* __restrict__ nb2,
    float* __restrict__ dout, const int* __restrict__ ptr)
{
    __shared__ __attribute__((aligned(16))) ushort catb[32][CP];
    __shared__ __attribute__((aligned(16))) ushort h1b[32][HP];

    const int t   = threadIdx.x;
    const int l   = t & 63;
    const int w   = t >> 6;
    const int ch  = w & 1;
    const int eh  = w >> 1;
    const int r16 = l & 15;
    const int g   = l >> 4;
    const int nb  = blockIdx.x * 32;

    {
        int nd = t >> 3;
        int c  = (t & 7) << 5;
        int gn = nb + nd; if (gn >= N_NODES) gn = N_NODES - 1;
        if (c < 128) {
            if (NFB) {
                const short8v* spv = reinterpret_cast<const short8v*>(nfb + (size_t)gn * 128 + c);
#pragma unroll
                for (int i = 0; i < 4; ++i)
                    *reinterpret_cast<short8v*>(&catb[nd][c + (i << 3)]) = spv[i];
            } else {
                const float4* spv = reinterpret_cast<const float4*>(node_feat + (size_t)gn * 128 + c);
#pragma unroll
                for (int i = 0; i < 4; ++i) {
                    float4 a = spv[2 * i], b = spv[2 * i + 1];
                    uint4 u;
                    u.x = pkbf(a.x, a.y); u.y = pkbf(a.z, a.w);
                    u.z = pkbf(b.x, b.y); u.w = pkbf(b.z, b.w);
                    *reinterpret_cast<uint4*>(&catb[nd][c + (i << 3)]) = u;
                }
            }
        } else {
            const float4* spv = reinterpret_cast<const float4*>(dout + (size_t)gn * HID + (c - 128));
#pragma unroll
            for (int i = 0; i < 4; ++i) {
                float4 a = spv[2 * i], b = spv[2 * i + 1];
                uint4 u;
                u.x = pkbf(a.x, a.y); u.y = pkbf(a.z, a.w);
                u.z = pkbf(b.x, b.y); u.w = pkbf(b.z, b.w);
                *reinterpret_cast<uint4*>(&catb[nd][c + (i << 3)]) = u;
            }
        }
    }
    __syncthreads();

    const f32x4 zero = {0.f, 0.f, 0.f, 0.f};
    const short8v* pv1 = reinterpret_cast<const short8v*>(pkn1);
    const short8v* pv2 = reinterpret_cast<const short8v*>(pkn2);

    f32x4 acc[4];
#pragma unroll
    for (int nt = 0; nt < 4; ++nt) acc[nt] = zero;
    for (int kt = 0; kt < 8; ++kt) {
        short8v b = *reinterpret_cast<const short8v*>(&catb[(eh << 4) + r16][(kt << 5) + (g << 3)]);
#pragma unroll
        for (int nt = 0; nt < 4; ++nt) {
            short8v a = pv1[(((kt << 3) + (ch << 2) + nt) << 6) + l];
            acc[nt] = __builtin_amdgcn_mfma_f32_16x16x32_bf16(a, b, acc[nt], 0, 0, 0);
        }
    }
#pragma unroll
    for (int nt = 0; nt < 4; ++nt) {
        int cb = (ch << 6) + (nt << 4) + (g << 2);
        float4 bias = *reinterpret_cast<const float4*>(&nb1[cb]);
        int nd = (eh << 4) + r16;
        f32x4 v = acc[nt];
        uint2 p;
        p.x = pkbf(silu_f(v[0] + bias.x), silu_f(v[1] + bias.y));
        p.y = pkbf(silu_f(v[2] + bias.z), silu_f(v[3] + bias.w));
        *reinterpret_cast<uint2*>(&h1b[nd][cb]) = p;
    }
    __syncthreads();

#pragma unroll
    for (int nt = 0; nt < 4; ++nt) acc[nt] = zero;
    for (int kt = 0; kt < 4; ++kt) {
        short8v b = *reinterpret_cast<const short8v*>(&h1b[(eh << 4) + r16][(kt << 5) + (g << 3)]);
#pragma unroll
        for (int nt = 0; nt < 4; ++nt) {
            short8v a = pv2[(((kt << 3) + (ch << 2) + nt) << 6) + l];
            acc[nt] = __builtin_amdgcn_mfma_f32_16x16x32_bf16(a, b, acc[nt], 0, 0, 0);
        }
    }
    {
        int gw = nb + (eh << 4) + r16;
        if (gw < N_NODES) {
#pragma unroll
            for (int nt = 0; nt < 4; ++nt) {
                int cb = (ch << 6) + (nt << 4) + (g << 2);
                float4 bias = *reinterpret_cast<const float4*>(&nb2[cb]);
                f32x4 v = acc[nt];
                float4 o;
                o.x = v[0] + bias.x; o.y = v[1] + bias.y;
                o.z = v[2] + bias.z; o.w = v[3] + bias.w;
                *reinterpret_cast<float4*>(&dout[(size_t)gw * HID + cb]) = o;
            }
        }
    }

    if (t < 96) {
        int nd = t / 3, d = t - 3 * nd;
        int gn = nb + nd;
        if (gn < N_NODES) {
            size_t xi = XOFF + (size_t)gn * 3 + d;
            float dg = (float)(ptr[gn + 1] - ptr[gn]);
            dg = dg > 1.0f ? dg : 1.0f;
            dout[xi] = coord[(size_t)gn * 3 + d] + dout[xi] / dg;
        }
    }
}

extern "C" void kernel_launch(void* const* d_in, const int* in_sizes, int n_in,
                              void* d_out, int out_size, void* d_ws, size_t ws_size,
                              hipStream_t stream) {
    const float* node_feat = (const float*)d_in[0];
    const float* coord     = (const float*)d_in[1];
    const float* edge_feat = (const float*)d_in[2];
    const int*   src       = (const int*)d_in[3];
    const int*   dst       = (const int*)d_in[4];
    const float* eW1 = (const float*)d_in[5];
    const float* eb1 = (const float*)d_in[6];
    const float* eW2 = (const float*)d_in[7];
    const float* eb2 = (const float*)d_in[8];
    const float* nW1 = (const float*)d_in[9];
    const float* nb1 = (const float*)d_in[10];
    const float* nW2 = (const float*)d_in[11];
    const float* nb2 = (const float*)d_in[12];
    const float* cW1 = (const float*)d_in[13];
    const float* cb1 = (const float*)d_in[14];
    const float* cW2 = (const float*)d_in[15];

    float* out = (float*)d_out;
    char* base = (char*)d_ws;
    // ws layout (bytes):
    int*    ptrb   = (int*)base;                      // 0       .. 200064
    int*    part   = (int*)(base + 200064);           // 200064  .. 200320
    int*    ptr2   = (int*)(base + 200320);           // 200320  .. 400384
    ushort* pk1old = (ushort*)(base + 400384);        // 400384  .. 474112
    ushort* pka    = (ushort*)(base + 474112);        // 474112  .. 506880
    ushort* pkb    = (ushort*)(base + 506880);        // 506880  .. 539648
    ushort* pk2    = (ushort*)(base + 539648);        // 539648  .. 572416
    ushort* pk3    = (ushort*)(base + 572416);        // 572416  .. 605184
    ushort* pkn1   = (ushort*)(base + 605184);        // 605184  .. 670720
    ushort* pkn2   = (ushort*)(base + 670720);        // 670720  .. 703488
    float*  cmb    = (float*)(base + 703488);         // 703488  .. 705536
    int*    perm   = (int*)(base + 705536);           // 705536  .. 3905536
    ushort* ybuf   = (ushort*)(base + 3905536);       // y: 25.6MB
    ushort* nfb2   = (ushort*)(base + 29505536);      // nfb: 12.8MB (after y)
    const size_t need_y    = 3905536 + (size_t)N_NODES * 256 * 2;   // 29,505,536
    const size_t need_nfb2 = 29505536 + (size_t)N_NODES * 128 * 2;  // 42,305,536
    const size_t need_nfb  = 3905536 + (size_t)N_NODES * 128 * 2;   // fallback slot
    const size_t need_perm = 3905536;
    const bool use_y    = ws_size >= need_y;
    const bool use_nfb2 = use_y && ws_size >= need_nfb2;
    const bool use_nfb  = !use_y && ws_size >= need_nfb;
    const bool use_perm = ws_size >= need_perm;

    hipMemsetAsync(d_out, 0, (size_t)out_size * sizeof(float), stream);
    hipMemsetAsync(d_ws, 0, 200064, stream);

    // prep + hist (+ nfb when space allows); nfb destination depends on path
    ushort* nfbdst = use_y ? nfb2 : ybuf;
    int do_nfb = use_y ? (use_nfb2 ? 1 : 0) : (use_nfb ? 1 : 0);
    int ph_ids = 19200 + E_TOTAL + (do_nfb ? N_NODES * 16 : 0);
    prep_kernel<<<(ph_ids + 255) / 256, 256, 0, stream>>>(
        eW1, eW2, cW1, nW1, nW2, eb1, node_feat, dst, ptrb,
        pk1old, pka, pkb, pk2, pk3, pkn1, pkn2, cmb, nfbdst, do_nfb);

    scan_a<<<49, 1024, 0, stream>>>(ptrb, part);
    scan_c2<<<49, 1024, 0, stream>>>(ptrb, part, ptr2);
    if (use_perm)
        scatter_kernel<<<(E_TOTAL + 255) / 256, 256, 0, stream>>>(dst, ptr2, perm);

    if (use_y) {
        ygemm_kernel<<<(N_NODES + 31) / 32, 256, 0, stream>>>(node_feat, pka, pkb, ybuf);
        edge2_kernel<<<E_TOTAL / EPB, 512, 0, stream>>>(
            ybuf, coord, edge_feat, src, dst, perm, cmb,
            pk2, pk3, eb2, cb1, cW2, out, out + XOFF);
        if (use_nfb2) {
            node_kernel<true><<<(N_NODES + 31) / 32, 256, 0, stream>>>(
                node_feat, nfb2, coord, pkn1, pkn2, nb1, nb2, out, ptrb);
        } else {
            node_kernel<false><<<(N_NODES + 31) / 32, 256, 0, stream>>>(
                node_feat, nfb2, coord, pkn1, pkn2, nb1, nb2, out, ptrb);
        }
    } else {
        // fallback: direct f32 node path (no y buffer) — node_kernel handles both
        node_kernel<false><<<(N_NODES + 31) / 32, 256, 0, stream>>>(
            node_feat, ybuf, coord, pkn1, pkn2, nb1, nb2, out, ptrb);
    }
}